// Round 10
// baseline (279.131 us; speedup 1.0000x reference)
//
#include <hip/hip_runtime.h>

typedef _Float16 f16;
typedef f16 half8 __attribute__((ext_vector_type(8)));
typedef float f32x4 __attribute__((ext_vector_type(4)));
typedef unsigned long long u64;
typedef unsigned int u32;
typedef unsigned short u16;

#define KD 8192
#define DIFF_OFF 4194304
#define EIND_OFF 4194305
#define PERP_OFF 4210689
#define LCAP 262144

// ---- ws layout (bytes) ----
// best u64[16384]@0 | Fv@131072 | eev@196608 | (spare)@229376 |
// counts@262144 | dpart f32[1024]@294912 | eemax@299008 | cnt@299012
// ---- d_out scratch (dead before k_out writes quantize) ----
// ehTf f16 frag-linear [512 tiles][8 kk][64 lane][8] @0      (4MB)
// xhTf f16 frag-linear [1024 tiles][8][64][8]        @4MB    (8MB)
// m1 u32[16384][16] @12582912 (1MB) | m2 u16[16384][16] @13631488 (512KB)
// list u32[LCAP] @14155776 (1MB)

__device__ inline u32 umin32(u32 a, u32 b) { return a < b ? a : b; }
__device__ inline u32 umax32(u32 a, u32 b) { return a > b ? a : b; }
__device__ inline u64 pack64(float d, unsigned col) {
  u32 u = __float_as_uint(d);
  u = (u >> 31) ? ~u : (u | 0x80000000u);
  return ((u64)u << 32) | col;
}
// exact distance chain — bit-identical to rounds 1-9 (validated absmax 0)
__device__ inline float exact_d(const float* __restrict__ x, const float* __restrict__ e,
                                int b, int hw, int col, float F, const float* __restrict__ eev) {
  float a = 0.f;
#pragma unroll 8
  for (int c = 0; c < 256; ++c)
    a = fmaf(x[((size_t)(b * 256 + c) << 10) + hw], e[(size_t)c * KD + col], a);
  float t = fmaf(-2.f, a, F);
  return t + eev[col];
}

// blocks 0..31: ee | 32..95: Fv | 96..607: ehTf | 608..1631: xhTf
__global__ __launch_bounds__(256) void k_prep(const float* __restrict__ x,
                                              const float* __restrict__ e,
                                              float* __restrict__ Fv,
                                              float* __restrict__ eev,
                                              u32* __restrict__ eemax,
                                              f16* __restrict__ ehTf,
                                              f16* __restrict__ xhTf) {
#pragma clang fp contract(off)
  __shared__ float sm[64][65];
  const int bid = blockIdx.x, tid = threadIdx.x;
  if (bid < 32) {              // ||e_k||^2, np sequential order (validated)
    int k = bid * 256 + tid;
    float s = 0.0f;
    for (int c = 0; c < 256; ++c) { float v = e[(size_t)c * KD + k]; float sq = v * v; s = s + sq; }
    eev[k] = s;
    atomicMax(eemax, __float_as_uint(s));
  } else if (bid < 96) {       // ||f_n||^2, numpy pairwise (validated)
    int n = (bid - 32) * 256 + tid;
    int b = n >> 10, hw = n & 1023;
    const float* px = x + ((size_t)b << 18) + hw;
    float sblk[2];
#pragma unroll
    for (int blk = 0; blk < 2; ++blk) {
      float r[8];
#pragma unroll
      for (int j = 0; j < 8; ++j) { float v = px[(size_t)(blk * 128 + j) << 10]; r[j] = v * v; }
      for (int i = 8; i < 128; i += 8) {
#pragma unroll
        for (int j = 0; j < 8; ++j) {
          float v = px[(size_t)(blk * 128 + i + j) << 10];
          float sq = v * v;
          r[j] = r[j] + sq;
        }
      }
      sblk[blk] = ((r[0] + r[1]) + (r[2] + r[3])) + ((r[4] + r[5]) + (r[6] + r[7]));
    }
    Fv[n] = sblk[0] + sblk[1];
  } else if (bid < 608) {      // ehTf fragment-linear from e[c][k]
    int t = bid - 96;
    int k0 = (t >> 2) * 64, c0 = (t & 3) * 64;
    int tx = tid & 63, ty = tid >> 6;
#pragma unroll
    for (int i = 0; i < 16; ++i) {
      int cl = i * 4 + ty;
      sm[cl][tx] = e[(size_t)(c0 + cl) * KD + k0 + tx];
    }
    __syncthreads();
#pragma unroll
    for (int p = 0; p < 2; ++p) {
      int i = tid + p * 256;
      int kl = i & 63, cg = i >> 6;
      int kkl = cg >> 2, gg = cg & 3;
      int chb = kkl * 32 + gg * 8;
      half8 h;
#pragma unroll
      for (int j = 0; j < 8; ++j) h[j] = (f16)sm[chb + j][kl];
      int tile = (k0 >> 4) + (kl >> 4);
      int kk = (c0 >> 5) + kkl;
      int lanef = gg * 16 + (kl & 15);
      *(half8*)(ehTf + ((size_t)(tile * 8 + kk) * 64 + lanef) * 8) = h;
    }
  } else {                     // xhTf fragment-linear from x[b][c][hw]
    int t = bid - 608;
    int b = t >> 6, rem = t & 63;
    int hw0 = (rem >> 2) * 64, c0 = (rem & 3) * 64;
    int tx = tid & 63, ty = tid >> 6;
#pragma unroll
    for (int i = 0; i < 16; ++i) {
      int cl = i * 4 + ty;
      sm[cl][tx] = x[((size_t)(b * 256 + c0 + cl) << 10) + hw0 + tx];
    }
    __syncthreads();
#pragma unroll
    for (int p = 0; p < 2; ++p) {
      int i = tid + p * 256;
      int nl = i & 63, cg = i >> 6;
      int kkl = cg >> 2, gg = cg & 3;
      int chb = kkl * 32 + gg * 8;
      half8 h;
#pragma unroll
      for (int j = 0; j < 8; ++j) h[j] = (f16)sm[chb + j][nl];
      int rt = b * 64 + (hw0 >> 4) + (nl >> 4);
      int kk = (c0 >> 5) + kkl;
      int lanef = gg * 16 + (nl & 15);
      *(half8*)(xhTf + ((size_t)(rt * 8 + kk) * 64 + lanef) * 8) = h;
    }
  }
}

// LDS-staged MFMA distance GEMM. Grid 2048 = rowblk(128; 128r) x colblk(16;
// 512c). 8 waves 2x4, wave-tile 64r x 128c (acc[4][8]). K staged in 8 steps
// of BK=32: 40 x 1KB fragment-blocks/step (A 8, B 32) double-buffered in LDS
// (80KB). T14 split: global loads for s+1 issue before MFMA(s), ds_write
// after (latency hidden); one barrier/step. Unique L2 traffic 320KB/WG.
// Epilogue: top-2 with 23-bit-prefix|col9 keys, cross-wave LDS fold.
__global__ __launch_bounds__(512, 2) void k_gemm(const f16* __restrict__ xhTf,
                                                 const f16* __restrict__ ehTf,
                                                 const float* __restrict__ eev,
                                                 u32* __restrict__ m1,
                                                 u16* __restrict__ m2) {
  __shared__ f16 ldsbuf[2 * 40 * 512];     // [buf][block][512 f16]
  __shared__ u32 red1[4][128];
  __shared__ u32 red2[4][128];
  const int tid = threadIdx.x;
  const int lane = tid & 63, w = tid >> 6;
  const int wm = w >> 2, wn = w & 3;
  const int l15 = lane & 15, g = lane >> 4;
  const int colblk = blockIdx.x & 15;
  const int rowblk = (int)blockIdx.x >> 4;

  // staging: wave w owns blocks [w*5, w*5+5): A blocks 0..7, B blocks 8..39
  const int blk0 = w * 5;
  const f16* gsrc[5];
#pragma unroll
  for (int i = 0; i < 5; ++i) {
    int b = blk0 + i;
    gsrc[i] = ((b < 8) ? (xhTf + (size_t)(rowblk * 8 + b) * 4096)
                       : (ehTf + (size_t)(colblk * 32 + (b - 8)) * 4096)) + lane * 8;
  }
  f16* lw = ldsbuf + blk0 * 512 + lane * 8;

  f32x4 acc[4][8];
#pragma unroll
  for (int i = 0; i < 4; ++i)
#pragma unroll
    for (int j = 0; j < 8; ++j) acc[i][j] = (f32x4){0.f, 0.f, 0.f, 0.f};

  // prologue: stage step 0 into buffer 0
  {
    uint4 st[5];
#pragma unroll
    for (int i = 0; i < 5; ++i) st[i] = *(const uint4*)(gsrc[i]);
#pragma unroll
    for (int i = 0; i < 5; ++i) *(uint4*)(lw + i * 512) = st[i];
  }
  __syncthreads();

  const f16* lrA = ldsbuf + (wm * 4) * 512 + lane * 8;
  const f16* lrB = ldsbuf + (8 + wn * 8) * 512 + lane * 8;

#pragma unroll
  for (int s = 0; s < 8; ++s) {
    const int cur = (s & 1) * (40 * 512);
    const int nxt = ((s + 1) & 1) * (40 * 512);
    uint4 stg[5];
    if (s < 7) {
#pragma unroll
      for (int i = 0; i < 5; ++i) stg[i] = *(const uint4*)(gsrc[i] + (s + 1) * 512);
    }
    half8 af[4], bf[8];
#pragma unroll
    for (int mt = 0; mt < 4; ++mt) af[mt] = *(const half8*)(lrA + cur + mt * 512);
#pragma unroll
    for (int nt = 0; nt < 8; ++nt) bf[nt] = *(const half8*)(lrB + cur + nt * 512);
#pragma unroll
    for (int mt = 0; mt < 4; ++mt)
#pragma unroll
      for (int nt = 0; nt < 8; ++nt)
        acc[mt][nt] = __builtin_amdgcn_mfma_f32_16x16x32_f16(af[mt], bf[nt], acc[mt][nt], 0, 0, 0);
    if (s < 7) {
#pragma unroll
      for (int i = 0; i < 5; ++i) *(uint4*)(lw + nxt + i * 512) = stg[i];
    }
    __syncthreads();
  }

  // epilogue: keys = float-bits(d16) top-23 | col9 (col-in-colblk)
  float ee16[8];
#pragma unroll
  for (int nt = 0; nt < 8; ++nt)
    ee16[nt] = eev[colblk * 512 + wn * 128 + nt * 16 + l15] + 16.0f;
#pragma unroll
  for (int mt = 0; mt < 4; ++mt) {
#pragma unroll
    for (int r = 0; r < 4; ++r) {
      u32 s1 = 0xFFFFFFFFu, s2 = 0xFFFFFFFFu;
#pragma unroll
      for (int nt = 0; nt < 8; ++nt) {
        float d16 = fmaf(-2.f, acc[mt][nt][r], ee16[nt]);
        u32 k = (__float_as_uint(d16) & 0xFFFFFE00u) | (u32)(wn * 128 + nt * 16 + l15);
        u32 t = umax32(s1, k);
        s1 = umin32(s1, k);
        s2 = umin32(s2, t);
      }
#pragma unroll
      for (int msk = 1; msk < 16; msk <<= 1) {
        u32 o1 = (u32)__shfl_xor((int)s1, msk, 64);
        u32 o2 = (u32)__shfl_xor((int)s2, msk, 64);
        u32 t = umax32(s1, o1);
        s1 = umin32(s1, o1);
        s2 = umin32(umin32(s2, o2), t);
      }
      if (l15 == 0) {
        int rl = wm * 64 + mt * 16 + g * 4 + r;
        red1[wn][rl] = s1;
        red2[wn][rl] = s2;
      }
    }
  }
  __syncthreads();
  if (tid < 128) {
    u32 k1 = red1[0][tid], k2 = red2[0][tid];
#pragma unroll
    for (int wv = 1; wv < 4; ++wv) {
      u32 a = red1[wv][tid], b2 = red2[wv][tid];
      u32 t = umax32(k1, a);
      k1 = umin32(k1, a);
      k2 = umin32(k2, umin32(t, b2));
    }
    int row = rowblk * 128 + tid;
    m1[(size_t)row * 16 + colblk] = k1;
    float d2 = __uint_as_float(k2 & 0xFFFFFE00u);          // d16-domain lower bound
    float tq = fmaxf(fminf(d2 * 2048.0f, 65535.f), 0.f);   // NaN-safe
    m2[(size_t)row * 16 + colblk] = (u16)(u32)tq;
  }
}

// one wave per row: window test over 16 colblk top1/top2; direct write when
// unambiguous; else exact rescore of in-window top1s + enqueue colblk tasks.
__global__ __launch_bounds__(256) void k_sel(const float* __restrict__ x,
                                             const float* __restrict__ e,
                                             const u32* __restrict__ m1,
                                             const u16* __restrict__ m2,
                                             const float* __restrict__ Fv,
                                             const float* __restrict__ eev,
                                             const u32* __restrict__ eemax,
                                             u64* __restrict__ best,
                                             u32* __restrict__ cnt,
                                             u32* __restrict__ list) {
  const int row = blockIdx.x * 4 + (threadIdx.x >> 6);
  const int lane = threadIdx.x & 63;
  u32 m1v = 0xFFFFFFFFu;
  u32 m2v = 0xFFFFu;
  if (lane < 16) {
    m1v = m1[(size_t)row * 16 + lane];
    m2v = (u32)m2[(size_t)row * 16 + lane];
  }
  u32 gk = m1v;
#pragma unroll
  for (int msk = 1; msk < 64; msk <<= 1) gk = umin32(gk, (u32)__shfl_xor((int)gk, msk, 64));
  const float F = Fv[row];
  const float eps = 0x1p-9f * sqrtf(F * __uint_as_float(*eemax)) + 4e-4f;
  const float thr = (__uint_as_float(gk & 0xFFFFFE00u) - 16.0f) + 2.f * eps + 2e-3f;

  const bool f1 = (lane < 16) && (__uint_as_float(m1v & 0xFFFFFE00u) - 16.0f <= thr);
  const bool trig = (lane < 16) && ((float)m2v * (1.0f / 2048.0f) - 16.0f <= thr);
  const u64 bal = __ballot(f1);
  const bool anyt = __any(trig);

  const int col = lane * 512 + (int)(m1v & 511u);
  const int b = row >> 10, hw = row & 1023;

  if (__popcll(bal) == 1 && !anyt) {
    if (f1) best[row] = (u64)(unsigned)col;        // unambiguous: key 0
  } else {
    if (f1) {
      float d = exact_d(x, e, b, hw, col, F, eev);
      atomicMin(&best[row], pack64(d, (unsigned)col));
    }
    if (trig) {
      u32 slot = atomicAdd(cnt, 1u);
      if (slot < LCAP) list[slot] = (u32)((row << 4) | lane);
      else {   // overflow fallback (correctness only, ~never)
        for (int j = 0; j < 512; ++j) {
          int cj = lane * 512 + j;
          float d = exact_d(x, e, b, hw, cj, F, eev);
          atomicMin(&best[row], pack64(d, (unsigned)cj));
        }
      }
    }
  }
}

// full-colblk (512-col) exact rescore: wave per task, 8 cols/lane
__global__ __launch_bounds__(256) void k_chunk(const float* __restrict__ x,
                                               const float* __restrict__ e,
                                               const float* __restrict__ Fv,
                                               const float* __restrict__ eev,
                                               const u32* __restrict__ cnt,
                                               const u32* __restrict__ list,
                                               u64* __restrict__ best) {
  u32 n = *cnt; if (n > LCAP) n = LCAP;
  const int lane = threadIdx.x & 63;
  for (u32 t = blockIdx.x * 4 + (threadIdx.x >> 6); t < n; t += gridDim.x * 4) {
    u32 v = list[t];
    int row = (int)(v >> 4), cb = (int)(v & 15u);
    int b = row >> 10, hw = row & 1023;
    float F = Fv[row];
    int base = cb * 512 + lane;
    float a[8];
#pragma unroll
    for (int q = 0; q < 8; ++q) a[q] = 0.f;
#pragma unroll 4
    for (int c = 0; c < 256; ++c) {
      float xv = x[((size_t)(b * 256 + c) << 10) + hw];
      const float* ep = e + (size_t)c * KD + base;
#pragma unroll
      for (int q = 0; q < 8; ++q) a[q] = fmaf(xv, ep[q * 64], a[q]);
    }
#pragma unroll
    for (int q = 0; q < 8; ++q) {
      int col = base + q * 64;
      float t2 = fmaf(-2.f, a[q], F);
      float d = t2 + eev[col];
      atomicMin(&best[row], pack64(d, (unsigned)col));
    }
  }
}

// quantize + straight-through + diff partials + eind + counts (fused k_ind)
__global__ __launch_bounds__(256) void k_out(const float* __restrict__ x,
                                             const float* __restrict__ e,
                                             const u64* __restrict__ best,
                                             float* __restrict__ out,
                                             float* __restrict__ dpart,
                                             int* __restrict__ counts) {
  __shared__ float sd[256];
  int tid = threadIdx.x;
  float local = 0.0f;
  for (size_t v = (size_t)blockIdx.x * 256 + tid; v < 1048576ull; v += 262144ull) {
    size_t i = v * 4;
    int hw = (int)(i & 1023);
    int c = (int)((i >> 10) & 255);
    int bb = (int)(i >> 18);
    int n = (bb << 10) + hw;
    u32 i0 = (u32)best[n], i1 = (u32)best[n + 1];
    u32 i2 = (u32)best[n + 2], i3 = (u32)best[n + 3];
    float4 xv = *(const float4*)(x + i);
    const float* ec = e + (size_t)c * KD;
    float d0 = ec[i0] - xv.x;
    float d1 = ec[i1] - xv.y;
    float d2 = ec[i2] - xv.z;
    float d3 = ec[i3] - xv.w;
    float4 o = {xv.x + d0, xv.y + d1, xv.z + d2, xv.w + d3};
    *(float4*)(out + i) = o;
    local += d0 * d0 + d1 * d1 + d2 * d2 + d3 * d3;
    if (c == 0) {
      float4 ef = {(float)i0, (float)i1, (float)i2, (float)i3};
      *(float4*)(out + EIND_OFF + n) = ef;
      atomicAdd(&counts[i0], 1);
      atomicAdd(&counts[i1], 1);
      atomicAdd(&counts[i2], 1);
      atomicAdd(&counts[i3], 1);
    }
  }
  sd[tid] = local;
  __syncthreads();
  for (int s = 128; s > 0; s >>= 1) {
    if (tid < s) sd[tid] += sd[tid + s];
    __syncthreads();
  }
  if (tid == 0) dpart[blockIdx.x] = sd[0];
}

__global__ __launch_bounds__(256) void k_perp(const int* __restrict__ counts,
                                              const float* __restrict__ dpart,
                                              float* __restrict__ out) {
  __shared__ float sd[256];
  int tid = threadIdx.x;
  float s = 0.0f;
  for (int k = tid; k < KD; k += 256) {
    float p = (float)counts[k] * (1.0f / 16384.0f);
    s += p * logf(p + 1e-10f);
  }
  sd[tid] = s;
  __syncthreads();
  for (int t = 128; t > 0; t >>= 1) {
    if (tid < t) sd[tid] += sd[tid + t];
    __syncthreads();
  }
  float S = sd[0];
  __syncthreads();
  float d = 0.0f;
  for (int t = tid; t < 1024; t += 256) d += dpart[t];
  sd[tid] = d;
  __syncthreads();
  for (int t = 128; t > 0; t >>= 1) {
    if (tid < t) sd[tid] += sd[tid + t];
    __syncthreads();
  }
  if (tid == 0) {
    out[DIFF_OFF] = sd[0] * (1.0f / 4194304.0f);
    out[PERP_OFF] = expf(-S);
  }
}

extern "C" void kernel_launch(void* const* d_in, const int* in_sizes, int n_in,
                              void* d_out, int out_size, void* d_ws, size_t ws_size,
                              hipStream_t stream) {
  const float* x = (const float*)d_in[0];   // [16,256,32,32]
  const float* e = (const float*)d_in[1];   // [256,8192]
  float* out = (float*)d_out;
  char* dc = (char*)d_out;
  char* ws = (char*)d_ws;

  u64* best = (u64*)(ws);
  float* Fv = (float*)(ws + 131072);
  float* eev = (float*)(ws + 196608);
  int* counts = (int*)(ws + 262144);
  float* dpart = (float*)(ws + 294912);
  u32* eemax = (u32*)(ws + 299008);
  u32* cnt = (u32*)(ws + 299012);

  f16* ehTf = (f16*)(dc);
  f16* xhTf = (f16*)(dc + 4194304);
  u32* m1 = (u32*)(dc + 12582912);
  u16* m2 = (u16*)(dc + 13631488);
  u32* list = (u32*)(dc + 14155776);

  hipMemsetAsync(best, 0xFF, 131072, stream);
  hipMemsetAsync(counts, 0, 36872, stream);   // counts+dpart+eemax+cnt

  k_prep<<<1632, 256, 0, stream>>>(x, e, Fv, eev, eemax, ehTf, xhTf);
  k_gemm<<<2048, 512, 0, stream>>>(xhTf, ehTf, eev, m1, m2);
  k_sel<<<4096, 256, 0, stream>>>(x, e, m1, m2, Fv, eev, eemax, best, cnt, list);
  k_chunk<<<1024, 256, 0, stream>>>(x, e, Fv, eev, cnt, list, best);
  k_out<<<1024, 256, 0, stream>>>(x, e, best, out, dpart, counts);
  k_perp<<<1, 256, 0, stream>>>(counts, dpart, out);
}

// Round 11
// 252.824 us; speedup vs baseline: 1.1041x; 1.1041x over previous
//
#include <hip/hip_runtime.h>

typedef _Float16 f16;
typedef f16 half8 __attribute__((ext_vector_type(8)));
typedef float f32x4 __attribute__((ext_vector_type(4)));
typedef unsigned long long u64;
typedef unsigned int u32;
typedef unsigned short u16;

#define KD 8192
#define DIFF_OFF 4194304
#define EIND_OFF 4194305
#define PERP_OFF 4210689
#define LCAP 262144

// ---- ws layout (bytes) ----
// best u64[16384]@0 | Fv@131072 | eev@196608 | idx16 u16[16384]@229376 |
// counts@262144 | dpart f32[1024]@294912 | eemax@299008 | cnt@299012
// ---- d_out scratch (dead before k_out writes quantize) ----
// ehTf f16 frag-linear [512 tiles][8 kk][64 lane][8] @0      (4MB)
// xhTf f16 frag-linear [1024 tiles][8][64][8]        @4MB    (8MB)
// m1 u32[16384][16] @12582912 (1MB) | m2 u16[16384][16] @13631488 (512KB)
// list u32[LCAP] @14155776 (1MB)

__device__ inline u32 umin32(u32 a, u32 b) { return a < b ? a : b; }
__device__ inline u32 umax32(u32 a, u32 b) { return a > b ? a : b; }
__device__ inline u64 pack64(float d, unsigned col) {
  u32 u = __float_as_uint(d);
  u = (u >> 31) ? ~u : (u | 0x80000000u);
  return ((u64)u << 32) | col;
}
// async global->LDS, 16B per lane; lds dest is wave-uniform base + lane*16
__device__ inline void gl16(const f16* g, f16* l) {
  __builtin_amdgcn_global_load_lds(
      (const __attribute__((address_space(1))) void*)g,
      (__attribute__((address_space(3))) void*)l, 16, 0, 0);
}
// exact distance chain — bit-identical to rounds 1-10 (validated absmax 0)
__device__ inline float exact_d(const float* __restrict__ x, const float* __restrict__ e,
                                int b, int hw, int col, float F, const float* __restrict__ eev) {
  float a = 0.f;
#pragma unroll 8
  for (int c = 0; c < 256; ++c)
    a = fmaf(x[((size_t)(b * 256 + c) << 10) + hw], e[(size_t)c * KD + col], a);
  float t = fmaf(-2.f, a, F);
  return t + eev[col];
}

// blocks 0..31: ee | 32..95: Fv | 96..607: ehTf | 608..1631: xhTf
__global__ __launch_bounds__(256) void k_prep(const float* __restrict__ x,
                                              const float* __restrict__ e,
                                              float* __restrict__ Fv,
                                              float* __restrict__ eev,
                                              u32* __restrict__ eemax,
                                              f16* __restrict__ ehTf,
                                              f16* __restrict__ xhTf) {
#pragma clang fp contract(off)
  __shared__ float sm[64][65];
  const int bid = blockIdx.x, tid = threadIdx.x;
  if (bid < 32) {              // ||e_k||^2, np sequential order (validated)
    int k = bid * 256 + tid;
    float s = 0.0f;
    for (int c = 0; c < 256; ++c) { float v = e[(size_t)c * KD + k]; float sq = v * v; s = s + sq; }
    eev[k] = s;
    atomicMax(eemax, __float_as_uint(s));
  } else if (bid < 96) {       // ||f_n||^2, numpy pairwise (validated)
    int n = (bid - 32) * 256 + tid;
    int b = n >> 10, hw = n & 1023;
    const float* px = x + ((size_t)b << 18) + hw;
    float sblk[2];
#pragma unroll
    for (int blk = 0; blk < 2; ++blk) {
      float r[8];
#pragma unroll
      for (int j = 0; j < 8; ++j) { float v = px[(size_t)(blk * 128 + j) << 10]; r[j] = v * v; }
      for (int i = 8; i < 128; i += 8) {
#pragma unroll
        for (int j = 0; j < 8; ++j) {
          float v = px[(size_t)(blk * 128 + i + j) << 10];
          float sq = v * v;
          r[j] = r[j] + sq;
        }
      }
      sblk[blk] = ((r[0] + r[1]) + (r[2] + r[3])) + ((r[4] + r[5]) + (r[6] + r[7]));
    }
    Fv[n] = sblk[0] + sblk[1];
  } else if (bid < 608) {      // ehTf fragment-linear from e[c][k]
    int t = bid - 96;
    int k0 = (t >> 2) * 64, c0 = (t & 3) * 64;
    int tx = tid & 63, ty = tid >> 6;
#pragma unroll
    for (int i = 0; i < 16; ++i) {
      int cl = i * 4 + ty;
      sm[cl][tx] = e[(size_t)(c0 + cl) * KD + k0 + tx];
    }
    __syncthreads();
#pragma unroll
    for (int p = 0; p < 2; ++p) {
      int i = tid + p * 256;
      int kl = i & 63, cg = i >> 6;
      int kkl = cg >> 2, gg = cg & 3;
      int chb = kkl * 32 + gg * 8;
      half8 h;
#pragma unroll
      for (int j = 0; j < 8; ++j) h[j] = (f16)sm[chb + j][kl];
      int tile = (k0 >> 4) + (kl >> 4);
      int kk = (c0 >> 5) + kkl;
      int lanef = gg * 16 + (kl & 15);
      *(half8*)(ehTf + ((size_t)(tile * 8 + kk) * 64 + lanef) * 8) = h;
    }
  } else {                     // xhTf fragment-linear from x[b][c][hw]
    int t = bid - 608;
    int b = t >> 6, rem = t & 63;
    int hw0 = (rem >> 2) * 64, c0 = (rem & 3) * 64;
    int tx = tid & 63, ty = tid >> 6;
#pragma unroll
    for (int i = 0; i < 16; ++i) {
      int cl = i * 4 + ty;
      sm[cl][tx] = x[((size_t)(b * 256 + c0 + cl) << 10) + hw0 + tx];
    }
    __syncthreads();
#pragma unroll
    for (int p = 0; p < 2; ++p) {
      int i = tid + p * 256;
      int nl = i & 63, cg = i >> 6;
      int kkl = cg >> 2, gg = cg & 3;
      int chb = kkl * 32 + gg * 8;
      half8 h;
#pragma unroll
      for (int j = 0; j < 8; ++j) h[j] = (f16)sm[chb + j][nl];
      int rt = b * 64 + (hw0 >> 4) + (nl >> 4);
      int kk = (c0 >> 5) + kkl;
      int lanef = gg * 16 + (nl & 15);
      *(half8*)(xhTf + ((size_t)(rt * 8 + kk) * 64 + lanef) * 8) = h;
    }
  }
}

// LDS-staged MFMA distance GEMM with global_load_lds (m97-style schedule).
// Grid 2048 = rowblk(128; 128r) x colblk(16; 512c). 8 waves 2x4, wave-tile
// 64r x 128c. K in 8 steps of BK=32: 40 x 1KB blocks/step, each staged by
// ONE global_load_lds_dwordx4 wave-instruction (5 per wave), double-buffered
// (80KB). Loads for s+1 issue before MFMA(s); barrier drains vmcnt.
// Epilogue: top-2 with 23-bit-prefix|col9 keys, cross-wave LDS fold.
__global__ __launch_bounds__(512, 2) void k_gemm(const f16* __restrict__ xhTf,
                                                 const f16* __restrict__ ehTf,
                                                 const float* __restrict__ eev,
                                                 u32* __restrict__ m1,
                                                 u16* __restrict__ m2) {
  __shared__ __align__(16) f16 ldsbuf[2 * 40 * 512];     // [buf][block][512 f16]
  __shared__ u32 red1[4][128];
  __shared__ u32 red2[4][128];
  const int tid = threadIdx.x;
  const int lane = tid & 63, w = tid >> 6;
  const int wm = w >> 2, wn = w & 3;
  const int l15 = lane & 15, g = lane >> 4;
  const int colblk = blockIdx.x & 15;
  const int rowblk = (int)blockIdx.x >> 4;

  // staging: wave w owns blocks [w*5, w*5+5): A blocks 0..7, B blocks 8..39
  const int blk0 = w * 5;
  const f16* gsrc[5];
#pragma unroll
  for (int i = 0; i < 5; ++i) {
    int b = blk0 + i;
    gsrc[i] = ((b < 8) ? (xhTf + (size_t)(rowblk * 8 + b) * 4096)
                       : (ehTf + (size_t)(colblk * 32 + (b - 8)) * 4096)) + lane * 8;
  }

  f32x4 acc[4][8];
#pragma unroll
  for (int i = 0; i < 4; ++i)
#pragma unroll
    for (int j = 0; j < 8; ++j) acc[i][j] = (f32x4){0.f, 0.f, 0.f, 0.f};

  // prologue: stage step 0 into buffer 0 (one wave-load per block)
#pragma unroll
  for (int i = 0; i < 5; ++i) gl16(gsrc[i], ldsbuf + (blk0 + i) * 512);
  __syncthreads();

  const f16* lrA = ldsbuf + (wm * 4) * 512 + lane * 8;
  const f16* lrB = ldsbuf + (8 + wn * 8) * 512 + lane * 8;

#pragma unroll
  for (int s = 0; s < 8; ++s) {
    const int cur = (s & 1) * (40 * 512);
    const int nxt = ((s + 1) & 1) * (40 * 512);
    if (s < 7) {
#pragma unroll
      for (int i = 0; i < 5; ++i)
        gl16(gsrc[i] + (s + 1) * 512, ldsbuf + nxt + (blk0 + i) * 512);
    }
    half8 af[4], bf[8];
#pragma unroll
    for (int mt = 0; mt < 4; ++mt) af[mt] = *(const half8*)(lrA + cur + mt * 512);
#pragma unroll
    for (int nt = 0; nt < 8; ++nt) bf[nt] = *(const half8*)(lrB + cur + nt * 512);
#pragma unroll
    for (int mt = 0; mt < 4; ++mt)
#pragma unroll
      for (int nt = 0; nt < 8; ++nt)
        acc[mt][nt] = __builtin_amdgcn_mfma_f32_16x16x32_f16(af[mt], bf[nt], acc[mt][nt], 0, 0, 0);
    __syncthreads();
  }

  // epilogue: keys = float-bits(d16) top-23 | col9 (col-in-colblk)
  float ee16[8];
#pragma unroll
  for (int nt = 0; nt < 8; ++nt)
    ee16[nt] = eev[colblk * 512 + wn * 128 + nt * 16 + l15] + 16.0f;
#pragma unroll
  for (int mt = 0; mt < 4; ++mt) {
#pragma unroll
    for (int r = 0; r < 4; ++r) {
      u32 s1 = 0xFFFFFFFFu, s2 = 0xFFFFFFFFu;
#pragma unroll
      for (int nt = 0; nt < 8; ++nt) {
        float d16 = fmaf(-2.f, acc[mt][nt][r], ee16[nt]);
        u32 k = (__float_as_uint(d16) & 0xFFFFFE00u) | (u32)(wn * 128 + nt * 16 + l15);
        u32 t = umax32(s1, k);
        s1 = umin32(s1, k);
        s2 = umin32(s2, t);
      }
#pragma unroll
      for (int msk = 1; msk < 16; msk <<= 1) {
        u32 o1 = (u32)__shfl_xor((int)s1, msk, 64);
        u32 o2 = (u32)__shfl_xor((int)s2, msk, 64);
        u32 t = umax32(s1, o1);
        s1 = umin32(s1, o1);
        s2 = umin32(umin32(s2, o2), t);
      }
      if (l15 == 0) {
        int rl = wm * 64 + mt * 16 + g * 4 + r;
        red1[wn][rl] = s1;
        red2[wn][rl] = s2;
      }
    }
  }
  __syncthreads();
  if (tid < 128) {
    u32 k1 = red1[0][tid], k2 = red2[0][tid];
#pragma unroll
    for (int wv = 1; wv < 4; ++wv) {
      u32 a = red1[wv][tid], b2 = red2[wv][tid];
      u32 t = umax32(k1, a);
      k1 = umin32(k1, a);
      k2 = umin32(k2, umin32(t, b2));
    }
    int row = rowblk * 128 + tid;
    m1[(size_t)row * 16 + colblk] = k1;
    float d2 = __uint_as_float(k2 & 0xFFFFFE00u);          // d16-domain lower bound
    float tq = fmaxf(fminf(d2 * 2048.0f, 65535.f), 0.f);   // NaN-safe
    m2[(size_t)row * 16 + colblk] = (u16)(u32)tq;
  }
}

// one wave per row: window test over 16 colblk top1/top2; direct write when
// unambiguous; else exact rescore of in-window top1s + enqueue colblk tasks.
__global__ __launch_bounds__(256) void k_sel(const float* __restrict__ x,
                                             const float* __restrict__ e,
                                             const u32* __restrict__ m1,
                                             const u16* __restrict__ m2,
                                             const float* __restrict__ Fv,
                                             const float* __restrict__ eev,
                                             const u32* __restrict__ eemax,
                                             u64* __restrict__ best,
                                             u32* __restrict__ cnt,
                                             u32* __restrict__ list) {
  const int row = blockIdx.x * 4 + (threadIdx.x >> 6);
  const int lane = threadIdx.x & 63;
  u32 m1v = 0xFFFFFFFFu;
  u32 m2v = 0xFFFFu;
  if (lane < 16) {
    m1v = m1[(size_t)row * 16 + lane];
    m2v = (u32)m2[(size_t)row * 16 + lane];
  }
  u32 gk = m1v;
#pragma unroll
  for (int msk = 1; msk < 64; msk <<= 1) gk = umin32(gk, (u32)__shfl_xor((int)gk, msk, 64));
  const float F = Fv[row];
  const float eps = 0x1p-9f * sqrtf(F * __uint_as_float(*eemax)) + 4e-4f;
  const float thr = (__uint_as_float(gk & 0xFFFFFE00u) - 16.0f) + 2.f * eps + 2e-3f;

  const bool f1 = (lane < 16) && (__uint_as_float(m1v & 0xFFFFFE00u) - 16.0f <= thr);
  const bool trig = (lane < 16) && ((float)m2v * (1.0f / 2048.0f) - 16.0f <= thr);
  const u64 bal = __ballot(f1);
  const bool anyt = __any(trig);

  const int col = lane * 512 + (int)(m1v & 511u);
  const int b = row >> 10, hw = row & 1023;

  if (__popcll(bal) == 1 && !anyt) {
    if (f1) best[row] = (u64)(unsigned)col;        // unambiguous: key 0
  } else {
    if (f1) {
      float d = exact_d(x, e, b, hw, col, F, eev);
      atomicMin(&best[row], pack64(d, (unsigned)col));
    }
    if (trig) {
      u32 slot = atomicAdd(cnt, 1u);
      if (slot < LCAP) list[slot] = (u32)((row << 4) | lane);
      else {   // overflow fallback (correctness only, ~never)
        for (int j = 0; j < 512; ++j) {
          int cj = lane * 512 + j;
          float d = exact_d(x, e, b, hw, cj, F, eev);
          atomicMin(&best[row], pack64(d, (unsigned)cj));
        }
      }
    }
  }
}

// full-colblk (512-col) exact rescore: wave per task, 8 cols/lane
__global__ __launch_bounds__(256) void k_chunk(const float* __restrict__ x,
                                               const float* __restrict__ e,
                                               const float* __restrict__ Fv,
                                               const float* __restrict__ eev,
                                               const u32* __restrict__ cnt,
                                               const u32* __restrict__ list,
                                               u64* __restrict__ best) {
  u32 n = *cnt; if (n > LCAP) n = LCAP;
  const int lane = threadIdx.x & 63;
  for (u32 t = blockIdx.x * 4 + (threadIdx.x >> 6); t < n; t += gridDim.x * 4) {
    u32 v = list[t];
    int row = (int)(v >> 4), cb = (int)(v & 15u);
    int b = row >> 10, hw = row & 1023;
    float F = Fv[row];
    int base = cb * 512 + lane;
    float a[8];
#pragma unroll
    for (int q = 0; q < 8; ++q) a[q] = 0.f;
#pragma unroll 4
    for (int c = 0; c < 256; ++c) {
      float xv = x[((size_t)(b * 256 + c) << 10) + hw];
      const float* ep = e + (size_t)c * KD + base;
#pragma unroll
      for (int q = 0; q < 8; ++q) a[q] = fmaf(xv, ep[q * 64], a[q]);
    }
#pragma unroll
    for (int q = 0; q < 8; ++q) {
      int col = base + q * 64;
      float t2 = fmaf(-2.f, a[q], F);
      float d = t2 + eev[col];
      atomicMin(&best[row], pack64(d, (unsigned)col));
    }
  }
}

// extract idx (u16) + eind + counts
__global__ __launch_bounds__(256) void k_ind(const u64* __restrict__ best,
                                             u16* __restrict__ idx16,
                                             int* __restrict__ counts,
                                             float* __restrict__ out) {
  int n = blockIdx.x * 256 + threadIdx.x;
  u32 idx = (u32)(best[n] & 0xFFFFFFFFull);
  idx16[n] = (u16)idx;
  out[EIND_OFF + n] = (float)idx;
  atomicAdd(&counts[idx], 1);
}

// quantize + straight-through + diff partials (float4-vectorized)
__global__ __launch_bounds__(256) void k_out(const float* __restrict__ x,
                                             const float* __restrict__ e,
                                             const u16* __restrict__ idx16,
                                             float* __restrict__ out,
                                             float* __restrict__ dpart) {
  __shared__ float sd[256];
  int tid = threadIdx.x;
  float local = 0.0f;
  for (size_t v = (size_t)blockIdx.x * 256 + tid; v < 1048576ull; v += 262144ull) {
    size_t i = v * 4;
    int hw = (int)(i & 1023);
    int c = (int)((i >> 10) & 255);
    int bb = (int)(i >> 18);
    int n = (bb << 10) + hw;
    ushort4 id4 = *(const ushort4*)(idx16 + n);
    float4 xv = *(const float4*)(x + i);
    const float* ec = e + (size_t)c * KD;
    float d0 = ec[id4.x] - xv.x;
    float d1 = ec[id4.y] - xv.y;
    float d2 = ec[id4.z] - xv.z;
    float d3 = ec[id4.w] - xv.w;
    float4 o = {xv.x + d0, xv.y + d1, xv.z + d2, xv.w + d3};
    *(float4*)(out + i) = o;
    local += d0 * d0 + d1 * d1 + d2 * d2 + d3 * d3;
  }
  sd[tid] = local;
  __syncthreads();
  for (int s = 128; s > 0; s >>= 1) {
    if (tid < s) sd[tid] += sd[tid + s];
    __syncthreads();
  }
  if (tid == 0) dpart[blockIdx.x] = sd[0];
}

__global__ __launch_bounds__(256) void k_perp(const int* __restrict__ counts,
                                              const float* __restrict__ dpart,
                                              float* __restrict__ out) {
  __shared__ float sd[256];
  int tid = threadIdx.x;
  float s = 0.0f;
  for (int k = tid; k < KD; k += 256) {
    float p = (float)counts[k] * (1.0f / 16384.0f);
    s += p * logf(p + 1e-10f);
  }
  sd[tid] = s;
  __syncthreads();
  for (int t = 128; t > 0; t >>= 1) {
    if (tid < t) sd[tid] += sd[tid + t];
    __syncthreads();
  }
  float S = sd[0];
  __syncthreads();
  float d = 0.0f;
  for (int t = tid; t < 1024; t += 256) d += dpart[t];
  sd[tid] = d;
  __syncthreads();
  for (int t = 128; t > 0; t >>= 1) {
    if (tid < t) sd[tid] += sd[tid + t];
    __syncthreads();
  }
  if (tid == 0) {
    out[DIFF_OFF] = sd[0] * (1.0f / 4194304.0f);
    out[PERP_OFF] = expf(-S);
  }
}

extern "C" void kernel_launch(void* const* d_in, const int* in_sizes, int n_in,
                              void* d_out, int out_size, void* d_ws, size_t ws_size,
                              hipStream_t stream) {
  const float* x = (const float*)d_in[0];   // [16,256,32,32]
  const float* e = (const float*)d_in[1];   // [256,8192]
  float* out = (float*)d_out;
  char* dc = (char*)d_out;
  char* ws = (char*)d_ws;

  u64* best = (u64*)(ws);
  float* Fv = (float*)(ws + 131072);
  float* eev = (float*)(ws + 196608);
  u16* idx16 = (u16*)(ws + 229376);
  int* counts = (int*)(ws + 262144);
  float* dpart = (float*)(ws + 294912);
  u32* eemax = (u32*)(ws + 299008);
  u32* cnt = (u32*)(ws + 299012);

  f16* ehTf = (f16*)(dc);
  f16* xhTf = (f16*)(dc + 4194304);
  u32* m1 = (u32*)(dc + 12582912);
  u16* m2 = (u16*)(dc + 13631488);
  u32* list = (u32*)(dc + 14155776);

  hipMemsetAsync(best, 0xFF, 131072, stream);
  hipMemsetAsync(counts, 0, 36872, stream);   // counts+dpart+eemax+cnt

  k_prep<<<1632, 256, 0, stream>>>(x, e, Fv, eev, eemax, ehTf, xhTf);
  k_gemm<<<2048, 512, 0, stream>>>(xhTf, ehTf, eev, m1, m2);
  k_sel<<<4096, 256, 0, stream>>>(x, e, m1, m2, Fv, eev, eemax, best, cnt, list);
  k_chunk<<<1024, 256, 0, stream>>>(x, e, Fv, eev, cnt, list, best);
  k_ind<<<64, 256, 0, stream>>>(best, idx16, counts, out);
  k_out<<<1024, 256, 0, stream>>>(x, e, idx16, out, dpart);
  k_perp<<<1, 256, 0, stream>>>(counts, dpart, out);
}

// Round 12
// 234.550 us; speedup vs baseline: 1.1901x; 1.0779x over previous
//
#include <hip/hip_runtime.h>

typedef _Float16 f16;
typedef f16 half8 __attribute__((ext_vector_type(8)));
typedef float f32x4 __attribute__((ext_vector_type(4)));
typedef unsigned long long u64;
typedef unsigned int u32;
typedef unsigned short u16;

#define KD 8192
#define DIFF_OFF 4194304
#define EIND_OFF 4194305
#define PERP_OFF 4210689
#define LCAP 262144

// ---- ws layout (bytes) ----
// best u64[16384]@0 | Fv@131072 | eev@196608 | idx16 u16[16384]@229376 |
// counts@262144 | dpart f32[1024]@294912 | eemax@299008 | cnt@299012
// ---- d_out scratch (dead before k_out writes quantize) ----
// ehTf f16 frag-linear [512 tiles][8 kk][64 lane][8] @0      (4MB)
// xhTf f16 frag-linear [1024 tiles][8][64][8]        @4MB    (8MB)
// m1 u32[16384][32] @12582912 (2MB) | m2 u16[16384][32] @14680064 (1MB)
// list u32[LCAP] @15728640 (1MB)   (ends 16777216 <= out bytes 16842760)

__device__ inline u32 umin32(u32 a, u32 b) { return a < b ? a : b; }
__device__ inline u32 umax32(u32 a, u32 b) { return a > b ? a : b; }
__device__ inline u64 pack64(float d, unsigned col) {
  u32 u = __float_as_uint(d);
  u = (u >> 31) ? ~u : (u | 0x80000000u);
  return ((u64)u << 32) | col;
}
// async global->LDS, 16B per lane; lds dest is wave-uniform base + lane*16
__device__ inline void gl16(const f16* g, f16* l) {
  __builtin_amdgcn_global_load_lds(
      (const __attribute__((address_space(1))) void*)g,
      (__attribute__((address_space(3))) void*)l, 16, 0, 0);
}
// exact distance chain — bit-identical to rounds 1-11 (validated absmax 0)
__device__ inline float exact_d(const float* __restrict__ x, const float* __restrict__ e,
                                int b, int hw, int col, float F, const float* __restrict__ eev) {
  float a = 0.f;
#pragma unroll 8
  for (int c = 0; c < 256; ++c)
    a = fmaf(x[((size_t)(b * 256 + c) << 10) + hw], e[(size_t)c * KD + col], a);
  float t = fmaf(-2.f, a, F);
  return t + eev[col];
}

// blocks 0..31: ee | 32..95: Fv | 96..607: ehTf | 608..1631: xhTf
__global__ __launch_bounds__(256) void k_prep(const float* __restrict__ x,
                                              const float* __restrict__ e,
                                              float* __restrict__ Fv,
                                              float* __restrict__ eev,
                                              u32* __restrict__ eemax,
                                              f16* __restrict__ ehTf,
                                              f16* __restrict__ xhTf) {
#pragma clang fp contract(off)
  __shared__ float sm[64][65];
  const int bid = blockIdx.x, tid = threadIdx.x;
  if (bid < 32) {              // ||e_k||^2, np sequential order (validated)
    int k = bid * 256 + tid;
    float s = 0.0f;
    for (int c = 0; c < 256; ++c) { float v = e[(size_t)c * KD + k]; float sq = v * v; s = s + sq; }
    eev[k] = s;
    atomicMax(eemax, __float_as_uint(s));
  } else if (bid < 96) {       // ||f_n||^2, numpy pairwise (validated)
    int n = (bid - 32) * 256 + tid;
    int b = n >> 10, hw = n & 1023;
    const float* px = x + ((size_t)b << 18) + hw;
    float sblk[2];
#pragma unroll
    for (int blk = 0; blk < 2; ++blk) {
      float r[8];
#pragma unroll
      for (int j = 0; j < 8; ++j) { float v = px[(size_t)(blk * 128 + j) << 10]; r[j] = v * v; }
      for (int i = 8; i < 128; i += 8) {
#pragma unroll
        for (int j = 0; j < 8; ++j) {
          float v = px[(size_t)(blk * 128 + i + j) << 10];
          float sq = v * v;
          r[j] = r[j] + sq;
        }
      }
      sblk[blk] = ((r[0] + r[1]) + (r[2] + r[3])) + ((r[4] + r[5]) + (r[6] + r[7]));
    }
    Fv[n] = sblk[0] + sblk[1];
  } else if (bid < 608) {      // ehTf fragment-linear from e[c][k]
    int t = bid - 96;
    int k0 = (t >> 2) * 64, c0 = (t & 3) * 64;
    int tx = tid & 63, ty = tid >> 6;
#pragma unroll
    for (int i = 0; i < 16; ++i) {
      int cl = i * 4 + ty;
      sm[cl][tx] = e[(size_t)(c0 + cl) * KD + k0 + tx];
    }
    __syncthreads();
#pragma unroll
    for (int p = 0; p < 2; ++p) {
      int i = tid + p * 256;
      int kl = i & 63, cg = i >> 6;
      int kkl = cg >> 2, gg = cg & 3;
      int chb = kkl * 32 + gg * 8;
      half8 h;
#pragma unroll
      for (int j = 0; j < 8; ++j) h[j] = (f16)sm[chb + j][kl];
      int tile = (k0 >> 4) + (kl >> 4);
      int kk = (c0 >> 5) + kkl;
      int lanef = gg * 16 + (kl & 15);
      *(half8*)(ehTf + ((size_t)(tile * 8 + kk) * 64 + lanef) * 8) = h;
    }
  } else {                     // xhTf fragment-linear from x[b][c][hw]
    int t = bid - 608;
    int b = t >> 6, rem = t & 63;
    int hw0 = (rem >> 2) * 64, c0 = (rem & 3) * 64;
    int tx = tid & 63, ty = tid >> 6;
#pragma unroll
    for (int i = 0; i < 16; ++i) {
      int cl = i * 4 + ty;
      sm[cl][tx] = x[((size_t)(b * 256 + c0 + cl) << 10) + hw0 + tx];
    }
    __syncthreads();
#pragma unroll
    for (int p = 0; p < 2; ++p) {
      int i = tid + p * 256;
      int nl = i & 63, cg = i >> 6;
      int kkl = cg >> 2, gg = cg & 3;
      int chb = kkl * 32 + gg * 8;
      half8 h;
#pragma unroll
      for (int j = 0; j < 8; ++j) h[j] = (f16)sm[chb + j][nl];
      int rt = b * 64 + (hw0 >> 4) + (nl >> 4);
      int kk = (c0 >> 5) + kkl;
      int lanef = gg * 16 + (nl & 15);
      *(half8*)(xhTf + ((size_t)(rt * 8 + kk) * 64 + lanef) * 8) = h;
    }
  }
}

// m97-geometry MFMA distance GEMM. Grid 4096 = rowblk(128; 128r) x colblk(32;
// 256c). 8 waves 2x4, wave-tile 64x64 (acc[4][4]=64 VGPR ->
// launch_bounds(512,4) => 2 WGs/CU, 4 waves/SIMD co-resident). BK=32, 8 steps;
// 24 x 1KB blocks/step staged by gl16 (3/wave), double-buffered (48KB+4KB red).
// Epilogue: top-2 with 24-bit-prefix|col8 keys (col8 = col-in-256-colblk),
// cross-wave LDS fold -> m1 u32[row][32], m2 u16[row][32] (r6 format).
__global__ __launch_bounds__(512, 4) void k_gemm(const f16* __restrict__ xhTf,
                                                 const f16* __restrict__ ehTf,
                                                 const float* __restrict__ eev,
                                                 u32* __restrict__ m1,
                                                 u16* __restrict__ m2) {
  __shared__ __align__(16) f16 ldsbuf[2 * 24 * 512];     // [buf][block][512 f16]
  __shared__ u32 red1[4][128];
  __shared__ u32 red2[4][128];
  const int tid = threadIdx.x;
  const int lane = tid & 63, w = tid >> 6;
  const int wm = w >> 2, wn = w & 3;
  const int l15 = lane & 15, g = lane >> 4;
  const int colblk = blockIdx.x & 31;
  const int rowblk = (int)blockIdx.x >> 5;

  // 24 blocks/step: A = row-tiles rowblk*8+i (i<8), B = col-tiles colblk*16+i (i<16)
  const int blk0 = w * 3;
  const f16* gsrc[3];
#pragma unroll
  for (int i = 0; i < 3; ++i) {
    int b = blk0 + i;
    gsrc[i] = ((b < 8) ? (xhTf + (size_t)(rowblk * 8 + b) * 4096)
                       : (ehTf + (size_t)(colblk * 16 + (b - 8)) * 4096)) + lane * 8;
  }

  f32x4 acc[4][4];
#pragma unroll
  for (int i = 0; i < 4; ++i)
#pragma unroll
    for (int j = 0; j < 4; ++j) acc[i][j] = (f32x4){0.f, 0.f, 0.f, 0.f};

  // prologue: stage step 0 into buffer 0
#pragma unroll
  for (int i = 0; i < 3; ++i) gl16(gsrc[i], ldsbuf + (blk0 + i) * 512);
  __syncthreads();

  const f16* lrA = ldsbuf + (wm * 4) * 512 + lane * 8;        // + mt*512
  const f16* lrB = ldsbuf + (8 + wn * 4) * 512 + lane * 8;    // + nt*512

#pragma unroll
  for (int s = 0; s < 8; ++s) {
    const int cur = (s & 1) * (24 * 512);
    const int nxt = ((s + 1) & 1) * (24 * 512);
    if (s < 7) {
#pragma unroll
      for (int i = 0; i < 3; ++i)
        gl16(gsrc[i] + (s + 1) * 512, ldsbuf + nxt + (blk0 + i) * 512);
    }
    half8 af[4], bf[4];
#pragma unroll
    for (int mt = 0; mt < 4; ++mt) af[mt] = *(const half8*)(lrA + cur + mt * 512);
#pragma unroll
    for (int nt = 0; nt < 4; ++nt) bf[nt] = *(const half8*)(lrB + cur + nt * 512);
#pragma unroll
    for (int mt = 0; mt < 4; ++mt)
#pragma unroll
      for (int nt = 0; nt < 4; ++nt)
        acc[mt][nt] = __builtin_amdgcn_mfma_f32_16x16x32_f16(af[mt], bf[nt], acc[mt][nt], 0, 0, 0);
    __syncthreads();
  }

  // epilogue: keys = float-bits(d16) top-24 | col8 (col-in-colblk)
  float ee16[4];
#pragma unroll
  for (int nt = 0; nt < 4; ++nt)
    ee16[nt] = eev[colblk * 256 + wn * 64 + nt * 16 + l15] + 16.0f;
#pragma unroll
  for (int mt = 0; mt < 4; ++mt) {
#pragma unroll
    for (int r = 0; r < 4; ++r) {
      u32 s1 = 0xFFFFFFFFu, s2 = 0xFFFFFFFFu;
#pragma unroll
      for (int nt = 0; nt < 4; ++nt) {
        float d16 = fmaf(-2.f, acc[mt][nt][r], ee16[nt]);
        u32 k = (__float_as_uint(d16) & 0xFFFFFF00u) | (u32)(wn * 64 + nt * 16 + l15);
        u32 t = umax32(s1, k);
        s1 = umin32(s1, k);
        s2 = umin32(s2, t);
      }
#pragma unroll
      for (int msk = 1; msk < 16; msk <<= 1) {
        u32 o1 = (u32)__shfl_xor((int)s1, msk, 64);
        u32 o2 = (u32)__shfl_xor((int)s2, msk, 64);
        u32 t = umax32(s1, o1);
        s1 = umin32(s1, o1);
        s2 = umin32(umin32(s2, o2), t);
      }
      if (l15 == 0) {
        int rl = wm * 64 + mt * 16 + g * 4 + r;
        red1[wn][rl] = s1;
        red2[wn][rl] = s2;
      }
    }
  }
  __syncthreads();
  if (tid < 128) {
    u32 k1 = red1[0][tid], k2 = red2[0][tid];
#pragma unroll
    for (int wv = 1; wv < 4; ++wv) {
      u32 a = red1[wv][tid], b2 = red2[wv][tid];
      u32 t = umax32(k1, a);
      k1 = umin32(k1, a);
      k2 = umin32(k2, umin32(t, b2));
    }
    int row = rowblk * 128 + tid;
    m1[(size_t)row * 32 + colblk] = k1;
    float d2 = __uint_as_float(k2 & 0xFFFFFF00u);          // d16-domain lower bound
    float tq = fmaxf(fminf(d2 * 2048.0f, 65535.f), 0.f);   // NaN-safe
    m2[(size_t)row * 32 + colblk] = (u16)(u32)tq;
  }
}

// one wave per row: window test over 32 colblk top1/top2; direct write when
// unambiguous; else exact rescore of in-window top1s + enqueue colblk tasks.
__global__ __launch_bounds__(256) void k_sel(const float* __restrict__ x,
                                             const float* __restrict__ e,
                                             const u32* __restrict__ m1,
                                             const u16* __restrict__ m2,
                                             const float* __restrict__ Fv,
                                             const float* __restrict__ eev,
                                             const u32* __restrict__ eemax,
                                             u64* __restrict__ best,
                                             u32* __restrict__ cnt,
                                             u32* __restrict__ list) {
  const int row = blockIdx.x * 4 + (threadIdx.x >> 6);
  const int lane = threadIdx.x & 63;
  u32 m1v = 0xFFFFFFFFu;
  u32 m2v = 0xFFFFu;
  if (lane < 32) {
    m1v = m1[(size_t)row * 32 + lane];
    m2v = (u32)m2[(size_t)row * 32 + lane];
  }
  u32 gk = m1v;
#pragma unroll
  for (int msk = 1; msk < 64; msk <<= 1) gk = umin32(gk, (u32)__shfl_xor((int)gk, msk, 64));
  const float F = Fv[row];
  const float eps = 0x1p-9f * sqrtf(F * __uint_as_float(*eemax)) + 4e-4f;
  const float thr = (__uint_as_float(gk & 0xFFFFFF00u) - 16.0f) + 2.f * eps + 1e-3f;

  const bool f1 = (lane < 32) && (__uint_as_float(m1v & 0xFFFFFF00u) - 16.0f <= thr);
  const bool trig = (lane < 32) && ((float)m2v * (1.0f / 2048.0f) - 16.0f <= thr);
  const u64 bal = __ballot(f1);
  const bool anyt = __any(trig);

  const int col = lane * 256 + (int)(m1v & 255u);
  const int b = row >> 10, hw = row & 1023;

  if (__popcll(bal) == 1 && !anyt) {
    if (f1) best[row] = (u64)(unsigned)col;        // unambiguous: key 0
  } else {
    if (f1) {
      float d = exact_d(x, e, b, hw, col, F, eev);
      atomicMin(&best[row], pack64(d, (unsigned)col));
    }
    if (trig) {
      u32 slot = atomicAdd(cnt, 1u);
      if (slot < LCAP) list[slot] = (u32)((row << 5) | lane);
      else {   // overflow fallback (correctness only, ~never)
        for (int j = 0; j < 256; ++j) {
          int cj = lane * 256 + j;
          float d = exact_d(x, e, b, hw, cj, F, eev);
          atomicMin(&best[row], pack64(d, (unsigned)cj));
        }
      }
    }
  }
}

// full-colblk (256-col) exact rescore: wave per task, 4 cols/lane
__global__ __launch_bounds__(256) void k_chunk(const float* __restrict__ x,
                                               const float* __restrict__ e,
                                               const float* __restrict__ Fv,
                                               const float* __restrict__ eev,
                                               const u32* __restrict__ cnt,
                                               const u32* __restrict__ list,
                                               u64* __restrict__ best) {
  u32 n = *cnt; if (n > LCAP) n = LCAP;
  const int lane = threadIdx.x & 63;
  for (u32 t = blockIdx.x * 4 + (threadIdx.x >> 6); t < n; t += gridDim.x * 4) {
    u32 v = list[t];
    int row = (int)(v >> 5), cb = (int)(v & 31u);
    int b = row >> 10, hw = row & 1023;
    float F = Fv[row];
    int base = cb * 256 + lane;
    float a0 = 0.f, a1 = 0.f, a2 = 0.f, a3 = 0.f;
#pragma unroll 8
    for (int c = 0; c < 256; ++c) {
      float xv = x[((size_t)(b * 256 + c) << 10) + hw];
      const float* ep = e + (size_t)c * KD + base;
      a0 = fmaf(xv, ep[0], a0);
      a1 = fmaf(xv, ep[64], a1);
      a2 = fmaf(xv, ep[128], a2);
      a3 = fmaf(xv, ep[192], a3);
    }
    float acc4[4] = {a0, a1, a2, a3};
#pragma unroll
    for (int q = 0; q < 4; ++q) {
      int col = base + q * 64;
      float t2 = fmaf(-2.f, acc4[q], F);
      float d = t2 + eev[col];
      atomicMin(&best[row], pack64(d, (unsigned)col));
    }
  }
}

// extract idx (u16) + eind + counts
__global__ __launch_bounds__(256) void k_ind(const u64* __restrict__ best,
                                             u16* __restrict__ idx16,
                                             int* __restrict__ counts,
                                             float* __restrict__ out) {
  int n = blockIdx.x * 256 + threadIdx.x;
  u32 idx = (u32)(best[n] & 0xFFFFFFFFull);
  idx16[n] = (u16)idx;
  out[EIND_OFF + n] = (float)idx;
  atomicAdd(&counts[idx], 1);
}

// quantize + straight-through + diff partials (float4-vectorized)
__global__ __launch_bounds__(256) void k_out(const float* __restrict__ x,
                                             const float* __restrict__ e,
                                             const u16* __restrict__ idx16,
                                             float* __restrict__ out,
                                             float* __restrict__ dpart) {
  __shared__ float sd[256];
  int tid = threadIdx.x;
  float local = 0.0f;
  for (size_t v = (size_t)blockIdx.x * 256 + tid; v < 1048576ull; v += 262144ull) {
    size_t i = v * 4;
    int hw = (int)(i & 1023);
    int c = (int)((i >> 10) & 255);
    int bb = (int)(i >> 18);
    int n = (bb << 10) + hw;
    ushort4 id4 = *(const ushort4*)(idx16 + n);
    float4 xv = *(const float4*)(x + i);
    const float* ec = e + (size_t)c * KD;
    float d0 = ec[id4.x] - xv.x;
    float d1 = ec[id4.y] - xv.y;
    float d2 = ec[id4.z] - xv.z;
    float d3 = ec[id4.w] - xv.w;
    float4 o = {xv.x + d0, xv.y + d1, xv.z + d2, xv.w + d3};
    *(float4*)(out + i) = o;
    local += d0 * d0 + d1 * d1 + d2 * d2 + d3 * d3;
  }
  sd[tid] = local;
  __syncthreads();
  for (int s = 128; s > 0; s >>= 1) {
    if (tid < s) sd[tid] += sd[tid + s];
    __syncthreads();
  }
  if (tid == 0) dpart[blockIdx.x] = sd[0];
}

__global__ __launch_bounds__(256) void k_perp(const int* __restrict__ counts,
                                              const float* __restrict__ dpart,
                                              float* __restrict__ out) {
  __shared__ float sd[256];
  int tid = threadIdx.x;
  float s = 0.0f;
  for (int k = tid; k < KD; k += 256) {
    float p = (float)counts[k] * (1.0f / 16384.0f);
    s += p * logf(p + 1e-10f);
  }
  sd[tid] = s;
  __syncthreads();
  for (int t = 128; t > 0; t >>= 1) {
    if (tid < t) sd[tid] += sd[tid + t];
    __syncthreads();
  }
  float S = sd[0];
  __syncthreads();
  float d = 0.0f;
  for (int t = tid; t < 1024; t += 256) d += dpart[t];
  sd[tid] = d;
  __syncthreads();
  for (int t = 128; t > 0; t >>= 1) {
    if (tid < t) sd[tid] += sd[tid + t];
    __syncthreads();
  }
  if (tid == 0) {
    out[DIFF_OFF] = sd[0] * (1.0f / 4194304.0f);
    out[PERP_OFF] = expf(-S);
  }
}

extern "C" void kernel_launch(void* const* d_in, const int* in_sizes, int n_in,
                              void* d_out, int out_size, void* d_ws, size_t ws_size,
                              hipStream_t stream) {
  const float* x = (const float*)d_in[0];   // [16,256,32,32]
  const float* e = (const float*)d_in[1];   // [256,8192]
  float* out = (float*)d_out;
  char* dc = (char*)d_out;
  char* ws = (char*)d_ws;

  u64* best = (u64*)(ws);
  float* Fv = (float*)(ws + 131072);
  float* eev = (float*)(ws + 196608);
  u16* idx16 = (u16*)(ws + 229376);
  int* counts = (int*)(ws + 262144);
  float* dpart = (float*)(ws + 294912);
  u32* eemax = (u32*)(ws + 299008);
  u32* cnt = (u32*)(ws + 299012);

  f16* ehTf = (f16*)(dc);
  f16* xhTf = (f16*)(dc + 4194304);
  u32* m1 = (u32*)(dc + 12582912);
  u16* m2 = (u16*)(dc + 14680064);
  u32* list = (u32*)(dc + 15728640);

  hipMemsetAsync(best, 0xFF, 131072, stream);
  hipMemsetAsync(counts, 0, 36872, stream);   // counts+dpart+eemax+cnt

  k_prep<<<1632, 256, 0, stream>>>(x, e, Fv, eev, eemax, ehTf, xhTf);
  k_gemm<<<4096, 512, 0, stream>>>(xhTf, ehTf, eev, m1, m2);
  k_sel<<<4096, 256, 0, stream>>>(x, e, m1, m2, Fv, eev, eemax, best, cnt, list);
  k_chunk<<<1024, 256, 0, stream>>>(x, e, Fv, eev, cnt, list, best);
  k_ind<<<64, 256, 0, stream>>>(best, idx16, counts, out);
  k_out<<<1024, 256, 0, stream>>>(x, e, idx16, out, dpart);
  k_perp<<<1, 256, 0, stream>>>(counts, dpart, out);
}

// Round 13
// 225.761 us; speedup vs baseline: 1.2364x; 1.0389x over previous
//
#include <hip/hip_runtime.h>

typedef _Float16 f16;
typedef f16 half8 __attribute__((ext_vector_type(8)));
typedef float f32x4 __attribute__((ext_vector_type(4)));
typedef unsigned long long u64;
typedef unsigned int u32;
typedef unsigned short u16;

#define KD 8192
#define DIFF_OFF 4194304
#define EIND_OFF 4194305
#define PERP_OFF 4210689
#define LCAP 262144

// ---- ws layout (bytes) ----
// best u64[16384]@0 | Fv@131072 | eev@196608 | idx16 u16[16384]@229376 |
// counts@262144 | dpart f32[1024]@294912 | eemax@299008 | cnt@299012
// ---- d_out scratch (dead before k_out writes quantize) ----
// ehTf f16 frag-linear [512 tiles][8 kk][64 lane][8] @0      (4MB)
// xhTf f16 frag-linear [1024 tiles][8][64][8]        @4MB    (8MB)
// m1 u32[32 colblk][16384 row] @12582912 (2MB)  (TRANSPOSED: contig writes)
// m2 u16[32 colblk][16384 row] @14680064 (1MB)
// list u32[LCAP] @15728640 (1MB)   (ends 16777216 <= out bytes 16842760)

__device__ inline u32 umin32(u32 a, u32 b) { return a < b ? a : b; }
__device__ inline u32 umax32(u32 a, u32 b) { return a > b ? a : b; }
__device__ inline u64 pack64(float d, unsigned col) {
  u32 u = __float_as_uint(d);
  u = (u >> 31) ? ~u : (u | 0x80000000u);
  return ((u64)u << 32) | col;
}
// async global->LDS, 16B per lane; lds dest is wave-uniform base + lane*16
__device__ inline void gl16(const f16* g, f16* l) {
  __builtin_amdgcn_global_load_lds(
      (const __attribute__((address_space(1))) void*)g,
      (__attribute__((address_space(3))) void*)l, 16, 0, 0);
}
// exact distance chain — bit-identical to rounds 1-12 (validated absmax 0)
__device__ inline float exact_d(const float* __restrict__ x, const float* __restrict__ e,
                                int b, int hw, int col, float F, const float* __restrict__ eev) {
  float a = 0.f;
#pragma unroll 8
  for (int c = 0; c < 256; ++c)
    a = fmaf(x[((size_t)(b * 256 + c) << 10) + hw], e[(size_t)c * KD + col], a);
  float t = fmaf(-2.f, a, F);
  return t + eev[col];
}

// blocks 0..31: ee | 32..95: Fv | 96..607: ehTf | 608..1631: xhTf
__global__ __launch_bounds__(256) void k_prep(const float* __restrict__ x,
                                              const float* __restrict__ e,
                                              float* __restrict__ Fv,
                                              float* __restrict__ eev,
                                              u32* __restrict__ eemax,
                                              f16* __restrict__ ehTf,
                                              f16* __restrict__ xhTf) {
#pragma clang fp contract(off)
  __shared__ float sm[64][65];
  const int bid = blockIdx.x, tid = threadIdx.x;
  if (bid < 32) {              // ||e_k||^2, np sequential order (validated)
    int k = bid * 256 + tid;
    float s = 0.0f;
    for (int c = 0; c < 256; ++c) { float v = e[(size_t)c * KD + k]; float sq = v * v; s = s + sq; }
    eev[k] = s;
    atomicMax(eemax, __float_as_uint(s));
  } else if (bid < 96) {       // ||f_n||^2, numpy pairwise (validated)
    int n = (bid - 32) * 256 + tid;
    int b = n >> 10, hw = n & 1023;
    const float* px = x + ((size_t)b << 18) + hw;
    float sblk[2];
#pragma unroll
    for (int blk = 0; blk < 2; ++blk) {
      float r[8];
#pragma unroll
      for (int j = 0; j < 8; ++j) { float v = px[(size_t)(blk * 128 + j) << 10]; r[j] = v * v; }
      for (int i = 8; i < 128; i += 8) {
#pragma unroll
        for (int j = 0; j < 8; ++j) {
          float v = px[(size_t)(blk * 128 + i + j) << 10];
          float sq = v * v;
          r[j] = r[j] + sq;
        }
      }
      sblk[blk] = ((r[0] + r[1]) + (r[2] + r[3])) + ((r[4] + r[5]) + (r[6] + r[7]));
    }
    Fv[n] = sblk[0] + sblk[1];
  } else if (bid < 608) {      // ehTf fragment-linear from e[c][k]
    int t = bid - 96;
    int k0 = (t >> 2) * 64, c0 = (t & 3) * 64;
    int tx = tid & 63, ty = tid >> 6;
#pragma unroll
    for (int i = 0; i < 16; ++i) {
      int cl = i * 4 + ty;
      sm[cl][tx] = e[(size_t)(c0 + cl) * KD + k0 + tx];
    }
    __syncthreads();
#pragma unroll
    for (int p = 0; p < 2; ++p) {
      int i = tid + p * 256;
      int kl = i & 63, cg = i >> 6;
      int kkl = cg >> 2, gg = cg & 3;
      int chb = kkl * 32 + gg * 8;
      half8 h;
#pragma unroll
      for (int j = 0; j < 8; ++j) h[j] = (f16)sm[chb + j][kl];
      int tile = (k0 >> 4) + (kl >> 4);
      int kk = (c0 >> 5) + kkl;
      int lanef = gg * 16 + (kl & 15);
      *(half8*)(ehTf + ((size_t)(tile * 8 + kk) * 64 + lanef) * 8) = h;
    }
  } else {                     // xhTf fragment-linear from x[b][c][hw]
    int t = bid - 608;
    int b = t >> 6, rem = t & 63;
    int hw0 = (rem >> 2) * 64, c0 = (rem & 3) * 64;
    int tx = tid & 63, ty = tid >> 6;
#pragma unroll
    for (int i = 0; i < 16; ++i) {
      int cl = i * 4 + ty;
      sm[cl][tx] = x[((size_t)(b * 256 + c0 + cl) << 10) + hw0 + tx];
    }
    __syncthreads();
#pragma unroll
    for (int p = 0; p < 2; ++p) {
      int i = tid + p * 256;
      int nl = i & 63, cg = i >> 6;
      int kkl = cg >> 2, gg = cg & 3;
      int chb = kkl * 32 + gg * 8;
      half8 h;
#pragma unroll
      for (int j = 0; j < 8; ++j) h[j] = (f16)sm[chb + j][nl];
      int rt = b * 64 + (hw0 >> 4) + (nl >> 4);
      int kk = (c0 >> 5) + kkl;
      int lanef = gg * 16 + (nl & 15);
      *(half8*)(xhTf + ((size_t)(rt * 8 + kk) * 64 + lanef) * 8) = h;
    }
  }
}

// m97-geometry MFMA distance GEMM. Grid 4096 = rowblk(128; 128r) x colblk(32;
// 256c). 8 waves 2x4, wave-tile 64x64; launch_bounds(512,4) => 2 WGs/CU.
// BK=32, 8 steps; 24 x 1KB blocks/step staged by gl16 (3/wave), dbuf LDS.
// setprio(1) around MFMA (T5: cross-WG K-loop/epilogue role split).
// Stores TRANSPOSED m1[colblk][row] / m2[colblk][row]: 512B+256B contiguous
// per WG -> no partial-line RMW (r12's 116MB WRITE_SIZE fix).
__global__ __launch_bounds__(512, 4) void k_gemm(const f16* __restrict__ xhTf,
                                                 const f16* __restrict__ ehTf,
                                                 const float* __restrict__ eev,
                                                 u32* __restrict__ m1,
                                                 u16* __restrict__ m2) {
  __shared__ __align__(16) f16 ldsbuf[2 * 24 * 512];     // [buf][block][512 f16]
  __shared__ u32 red1[4][128];
  __shared__ u32 red2[4][128];
  const int tid = threadIdx.x;
  const int lane = tid & 63, w = tid >> 6;
  const int wm = w >> 2, wn = w & 3;
  const int l15 = lane & 15, g = lane >> 4;
  const int colblk = blockIdx.x & 31;
  const int rowblk = (int)blockIdx.x >> 5;

  // 24 blocks/step: A = row-tiles rowblk*8+i (i<8), B = col-tiles colblk*16+i (i<16)
  const int blk0 = w * 3;
  const f16* gsrc[3];
#pragma unroll
  for (int i = 0; i < 3; ++i) {
    int b = blk0 + i;
    gsrc[i] = ((b < 8) ? (xhTf + (size_t)(rowblk * 8 + b) * 4096)
                       : (ehTf + (size_t)(colblk * 16 + (b - 8)) * 4096)) + lane * 8;
  }

  f32x4 acc[4][4];
#pragma unroll
  for (int i = 0; i < 4; ++i)
#pragma unroll
    for (int j = 0; j < 4; ++j) acc[i][j] = (f32x4){0.f, 0.f, 0.f, 0.f};

  // prologue: stage step 0 into buffer 0
#pragma unroll
  for (int i = 0; i < 3; ++i) gl16(gsrc[i], ldsbuf + (blk0 + i) * 512);
  __syncthreads();

  const f16* lrA = ldsbuf + (wm * 4) * 512 + lane * 8;        // + mt*512
  const f16* lrB = ldsbuf + (8 + wn * 4) * 512 + lane * 8;    // + nt*512

#pragma unroll
  for (int s = 0; s < 8; ++s) {
    const int cur = (s & 1) * (24 * 512);
    const int nxt = ((s + 1) & 1) * (24 * 512);
    if (s < 7) {
#pragma unroll
      for (int i = 0; i < 3; ++i)
        gl16(gsrc[i] + (s + 1) * 512, ldsbuf + nxt + (blk0 + i) * 512);
    }
    half8 af[4], bf[4];
#pragma unroll
    for (int mt = 0; mt < 4; ++mt) af[mt] = *(const half8*)(lrA + cur + mt * 512);
#pragma unroll
    for (int nt = 0; nt < 4; ++nt) bf[nt] = *(const half8*)(lrB + cur + nt * 512);
    __builtin_amdgcn_s_setprio(1);
#pragma unroll
    for (int mt = 0; mt < 4; ++mt)
#pragma unroll
      for (int nt = 0; nt < 4; ++nt)
        acc[mt][nt] = __builtin_amdgcn_mfma_f32_16x16x32_f16(af[mt], bf[nt], acc[mt][nt], 0, 0, 0);
    __builtin_amdgcn_s_setprio(0);
    __syncthreads();
  }

  // epilogue: keys = float-bits(d16) top-24 | col8 (col-in-colblk)
  float ee16[4];
#pragma unroll
  for (int nt = 0; nt < 4; ++nt)
    ee16[nt] = eev[colblk * 256 + wn * 64 + nt * 16 + l15] + 16.0f;
#pragma unroll
  for (int mt = 0; mt < 4; ++mt) {
#pragma unroll
    for (int r = 0; r < 4; ++r) {
      u32 s1 = 0xFFFFFFFFu, s2 = 0xFFFFFFFFu;
#pragma unroll
      for (int nt = 0; nt < 4; ++nt) {
        float d16 = fmaf(-2.f, acc[mt][nt][r], ee16[nt]);
        u32 k = (__float_as_uint(d16) & 0xFFFFFF00u) | (u32)(wn * 64 + nt * 16 + l15);
        u32 t = umax32(s1, k);
        s1 = umin32(s1, k);
        s2 = umin32(s2, t);
      }
#pragma unroll
      for (int msk = 1; msk < 16; msk <<= 1) {
        u32 o1 = (u32)__shfl_xor((int)s1, msk, 64);
        u32 o2 = (u32)__shfl_xor((int)s2, msk, 64);
        u32 t = umax32(s1, o1);
        s1 = umin32(s1, o1);
        s2 = umin32(umin32(s2, o2), t);
      }
      if (l15 == 0) {
        int rl = wm * 64 + mt * 16 + g * 4 + r;
        red1[wn][rl] = s1;
        red2[wn][rl] = s2;
      }
    }
  }
  __syncthreads();
  if (tid < 128) {
    u32 k1 = red1[0][tid], k2 = red2[0][tid];
#pragma unroll
    for (int wv = 1; wv < 4; ++wv) {
      u32 a = red1[wv][tid], b2 = red2[wv][tid];
      u32 t = umax32(k1, a);
      k1 = umin32(k1, a);
      k2 = umin32(k2, umin32(t, b2));
    }
    int row = rowblk * 128 + tid;
    m1[(size_t)colblk * 16384 + row] = k1;                 // contiguous 512B/WG
    float d2 = __uint_as_float(k2 & 0xFFFFFF00u);          // d16-domain lower bound
    float tq = fmaxf(fminf(d2 * 2048.0f, 65535.f), 0.f);   // NaN-safe
    m2[(size_t)colblk * 16384 + row] = (u16)(u32)tq;       // contiguous 256B/WG
  }
}

// one wave per row: window test over 32 colblk top1/top2 (transposed m1/m2,
// L2-resident); direct write when unambiguous; else exact rescore + enqueue.
__global__ __launch_bounds__(256) void k_sel(const float* __restrict__ x,
                                             const float* __restrict__ e,
                                             const u32* __restrict__ m1,
                                             const u16* __restrict__ m2,
                                             const float* __restrict__ Fv,
                                             const float* __restrict__ eev,
                                             const u32* __restrict__ eemax,
                                             u64* __restrict__ best,
                                             u32* __restrict__ cnt,
                                             u32* __restrict__ list) {
  const int row = blockIdx.x * 4 + (threadIdx.x >> 6);
  const int lane = threadIdx.x & 63;
  u32 m1v = 0xFFFFFFFFu;
  u32 m2v = 0xFFFFu;
  if (lane < 32) {
    m1v = m1[(size_t)lane * 16384 + row];
    m2v = (u32)m2[(size_t)lane * 16384 + row];
  }
  u32 gk = m1v;
#pragma unroll
  for (int msk = 1; msk < 64; msk <<= 1) gk = umin32(gk, (u32)__shfl_xor((int)gk, msk, 64));
  const float F = Fv[row];
  const float eps = 0x1p-9f * sqrtf(F * __uint_as_float(*eemax)) + 4e-4f;
  const float thr = (__uint_as_float(gk & 0xFFFFFF00u) - 16.0f) + 2.f * eps + 1e-3f;

  const bool f1 = (lane < 32) && (__uint_as_float(m1v & 0xFFFFFF00u) - 16.0f <= thr);
  const bool trig = (lane < 32) && ((float)m2v * (1.0f / 2048.0f) - 16.0f <= thr);
  const u64 bal = __ballot(f1);
  const bool anyt = __any(trig);

  const int col = lane * 256 + (int)(m1v & 255u);
  const int b = row >> 10, hw = row & 1023;

  if (__popcll(bal) == 1 && !anyt) {
    if (f1) best[row] = (u64)(unsigned)col;        // unambiguous: key 0
  } else {
    if (f1) {
      float d = exact_d(x, e, b, hw, col, F, eev);
      atomicMin(&best[row], pack64(d, (unsigned)col));
    }
    if (trig) {
      u32 slot = atomicAdd(cnt, 1u);
      if (slot < LCAP) list[slot] = (u32)((row << 5) | lane);
      else {   // overflow fallback (correctness only, ~never)
        for (int j = 0; j < 256; ++j) {
          int cj = lane * 256 + j;
          float d = exact_d(x, e, b, hw, cj, F, eev);
          atomicMin(&best[row], pack64(d, (unsigned)cj));
        }
      }
    }
  }
}

// full-colblk (256-col) exact rescore: wave per task, 4 cols/lane
__global__ __launch_bounds__(256) void k_chunk(const float* __restrict__ x,
                                               const float* __restrict__ e,
                                               const float* __restrict__ Fv,
                                               const float* __restrict__ eev,
                                               const u32* __restrict__ cnt,
                                               const u32* __restrict__ list,
                                               u64* __restrict__ best) {
  u32 n = *cnt; if (n > LCAP) n = LCAP;
  const int lane = threadIdx.x & 63;
  for (u32 t = blockIdx.x * 4 + (threadIdx.x >> 6); t < n; t += gridDim.x * 4) {
    u32 v = list[t];
    int row = (int)(v >> 5), cb = (int)(v & 31u);
    int b = row >> 10, hw = row & 1023;
    float F = Fv[row];
    int base = cb * 256 + lane;
    float a0 = 0.f, a1 = 0.f, a2 = 0.f, a3 = 0.f;
#pragma unroll 8
    for (int c = 0; c < 256; ++c) {
      float xv = x[((size_t)(b * 256 + c) << 10) + hw];
      const float* ep = e + (size_t)c * KD + base;
      a0 = fmaf(xv, ep[0], a0);
      a1 = fmaf(xv, ep[64], a1);
      a2 = fmaf(xv, ep[128], a2);
      a3 = fmaf(xv, ep[192], a3);
    }
    float acc4[4] = {a0, a1, a2, a3};
#pragma unroll
    for (int q = 0; q < 4; ++q) {
      int col = base + q * 64;
      float t2 = fmaf(-2.f, acc4[q], F);
      float d = t2 + eev[col];
      atomicMin(&best[row], pack64(d, (unsigned)col));
    }
  }
}

// extract idx (u16) + eind + counts
__global__ __launch_bounds__(256) void k_ind(const u64* __restrict__ best,
                                             u16* __restrict__ idx16,
                                             int* __restrict__ counts,
                                             float* __restrict__ out) {
  int n = blockIdx.x * 256 + threadIdx.x;
  u32 idx = (u32)(best[n] & 0xFFFFFFFFull);
  idx16[n] = (u16)idx;
  out[EIND_OFF + n] = (float)idx;
  atomicAdd(&counts[idx], 1);
}

// quantize + straight-through + diff partials (float4-vectorized)
__global__ __launch_bounds__(256) void k_out(const float* __restrict__ x,
                                             const float* __restrict__ e,
                                             const u16* __restrict__ idx16,
                                             float* __restrict__ out,
                                             float* __restrict__ dpart) {
  __shared__ float sd[256];
  int tid = threadIdx.x;
  float local = 0.0f;
  for (size_t v = (size_t)blockIdx.x * 256 + tid; v < 1048576ull; v += 262144ull) {
    size_t i = v * 4;
    int hw = (int)(i & 1023);
    int c = (int)((i >> 10) & 255);
    int bb = (int)(i >> 18);
    int n = (bb << 10) + hw;
    ushort4 id4 = *(const ushort4*)(idx16 + n);
    float4 xv = *(const float4*)(x + i);
    const float* ec = e + (size_t)c * KD;
    float d0 = ec[id4.x] - xv.x;
    float d1 = ec[id4.y] - xv.y;
    float d2 = ec[id4.z] - xv.z;
    float d3 = ec[id4.w] - xv.w;
    float4 o = {xv.x + d0, xv.y + d1, xv.z + d2, xv.w + d3};
    *(float4*)(out + i) = o;
    local += d0 * d0 + d1 * d1 + d2 * d2 + d3 * d3;
  }
  sd[tid] = local;
  __syncthreads();
  for (int s = 128; s > 0; s >>= 1) {
    if (tid < s) sd[tid] += sd[tid + s];
    __syncthreads();
  }
  if (tid == 0) dpart[blockIdx.x] = sd[0];
}

__global__ __launch_bounds__(256) void k_perp(const int* __restrict__ counts,
                                              const float* __restrict__ dpart,
                                              float* __restrict__ out) {
  __shared__ float sd[256];
  int tid = threadIdx.x;
  float s = 0.0f;
  for (int k = tid; k < KD; k += 256) {
    float p = (float)counts[k] * (1.0f / 16384.0f);
    s += p * logf(p + 1e-10f);
  }
  sd[tid] = s;
  __syncthreads();
  for (int t = 128; t > 0; t >>= 1) {
    if (tid < t) sd[tid] += sd[tid + t];
    __syncthreads();
  }
  float S = sd[0];
  __syncthreads();
  float d = 0.0f;
  for (int t = tid; t < 1024; t += 256) d += dpart[t];
  sd[tid] = d;
  __syncthreads();
  for (int t = 128; t > 0; t >>= 1) {
    if (tid < t) sd[tid] += sd[tid + t];
    __syncthreads();
  }
  if (tid == 0) {
    out[DIFF_OFF] = sd[0] * (1.0f / 4194304.0f);
    out[PERP_OFF] = expf(-S);
  }
}

extern "C" void kernel_launch(void* const* d_in, const int* in_sizes, int n_in,
                              void* d_out, int out_size, void* d_ws, size_t ws_size,
                              hipStream_t stream) {
  const float* x = (const float*)d_in[0];   // [16,256,32,32]
  const float* e = (const float*)d_in[1];   // [256,8192]
  float* out = (float*)d_out;
  char* dc = (char*)d_out;
  char* ws = (char*)d_ws;

  u64* best = (u64*)(ws);
  float* Fv = (float*)(ws + 131072);
  float* eev = (float*)(ws + 196608);
  u16* idx16 = (u16*)(ws + 229376);
  int* counts = (int*)(ws + 262144);
  float* dpart = (float*)(ws + 294912);
  u32* eemax = (u32*)(ws + 299008);
  u32* cnt = (u32*)(ws + 299012);

  f16* ehTf = (f16*)(dc);
  f16* xhTf = (f16*)(dc + 4194304);
  u32* m1 = (u32*)(dc + 12582912);
  u16* m2 = (u16*)(dc + 14680064);
  u32* list = (u32*)(dc + 15728640);

  hipMemsetAsync(best, 0xFF, 131072, stream);
  hipMemsetAsync(counts, 0, 36872, stream);   // counts+dpart+eemax+cnt

  k_prep<<<1632, 256, 0, stream>>>(x, e, Fv, eev, eemax, ehTf, xhTf);
  k_gemm<<<4096, 512, 0, stream>>>(xhTf, ehTf, eev, m1, m2);
  k_sel<<<4096, 256, 0, stream>>>(x, e, m1, m2, Fv, eev, eemax, best, cnt, list);
  k_chunk<<<1024, 256, 0, stream>>>(x, e, Fv, eev, cnt, list, best);
  k_ind<<<64, 256, 0, stream>>>(best, idx16, counts, out);
  k_out<<<1024, 256, 0, stream>>>(x, e, idx16, out, dpart);
  k_perp<<<1, 256, 0, stream>>>(counts, dpart, out);
}

// Round 14
// 224.071 us; speedup vs baseline: 1.2457x; 1.0075x over previous
//
#include <hip/hip_runtime.h>

typedef _Float16 f16;
typedef f16 half8 __attribute__((ext_vector_type(8)));
typedef float f32x4 __attribute__((ext_vector_type(4)));
typedef unsigned long long u64;
typedef unsigned int u32;
typedef unsigned short u16;

#define KD 8192
#define DIFF_OFF 4194304
#define EIND_OFF 4194305
#define PERP_OFF 4210689
#define LCAP 262144
#define BUFSZ (24 * 512)   // one staging buffer: 24 blocks x 512 f16

// ---- ws layout (bytes) ----
// best u64[16384]@0 | Fv@131072 | eev@196608 | idx16 u16[16384]@229376 |
// counts@262144 | dpart f32[1024]@294912 | eemax@299008 | cnt@299012
// ---- d_out scratch (dead before k_out writes quantize) ----
// ehTf f16 frag-linear [512 tiles][8 kk][64 lane][8] @0      (4MB)
// xhTf f16 frag-linear [1024 tiles][8][64][8]        @4MB    (8MB)
// m1 u32[32 colblk][16384 row] @12582912 (2MB)  (transposed: contig writes)
// m2 u16[32 colblk][16384 row] @14680064 (1MB)
// list u32[LCAP] @15728640 (1MB)

__device__ inline u32 umin32(u32 a, u32 b) { return a < b ? a : b; }
__device__ inline u32 umax32(u32 a, u32 b) { return a > b ? a : b; }
__device__ inline u64 pack64(float d, unsigned col) {
  u32 u = __float_as_uint(d);
  u = (u >> 31) ? ~u : (u | 0x80000000u);
  return ((u64)u << 32) | col;
}
// async global->LDS, 16B per lane; lds dest is wave-uniform base + lane*16
__device__ inline void gl16(const f16* g, f16* l) {
  __builtin_amdgcn_global_load_lds(
      (const __attribute__((address_space(1))) void*)g,
      (__attribute__((address_space(3))) void*)l, 16, 0, 0);
}
// exact distance chain — bit-identical to rounds 1-13 (validated absmax 0)
__device__ inline float exact_d(const float* __restrict__ x, const float* __restrict__ e,
                                int b, int hw, int col, float F, const float* __restrict__ eev) {
  float a = 0.f;
#pragma unroll 8
  for (int c = 0; c < 256; ++c)
    a = fmaf(x[((size_t)(b * 256 + c) << 10) + hw], e[(size_t)c * KD + col], a);
  float t = fmaf(-2.f, a, F);
  return t + eev[col];
}

// blocks 0..31: ee | 32..95: Fv | 96..607: ehTf | 608..1631: xhTf
__global__ __launch_bounds__(256) void k_prep(const float* __restrict__ x,
                                              const float* __restrict__ e,
                                              float* __restrict__ Fv,
                                              float* __restrict__ eev,
                                              u32* __restrict__ eemax,
                                              f16* __restrict__ ehTf,
                                              f16* __restrict__ xhTf) {
#pragma clang fp contract(off)
  __shared__ float sm[64][65];
  const int bid = blockIdx.x, tid = threadIdx.x;
  if (bid < 32) {              // ||e_k||^2, np sequential order (validated)
    int k = bid * 256 + tid;
    float s = 0.0f;
    for (int c = 0; c < 256; ++c) { float v = e[(size_t)c * KD + k]; float sq = v * v; s = s + sq; }
    eev[k] = s;
    atomicMax(eemax, __float_as_uint(s));
  } else if (bid < 96) {       // ||f_n||^2, numpy pairwise (validated)
    int n = (bid - 32) * 256 + tid;
    int b = n >> 10, hw = n & 1023;
    const float* px = x + ((size_t)b << 18) + hw;
    float sblk[2];
#pragma unroll
    for (int blk = 0; blk < 2; ++blk) {
      float r[8];
#pragma unroll
      for (int j = 0; j < 8; ++j) { float v = px[(size_t)(blk * 128 + j) << 10]; r[j] = v * v; }
      for (int i = 8; i < 128; i += 8) {
#pragma unroll
        for (int j = 0; j < 8; ++j) {
          float v = px[(size_t)(blk * 128 + i + j) << 10];
          float sq = v * v;
          r[j] = r[j] + sq;
        }
      }
      sblk[blk] = ((r[0] + r[1]) + (r[2] + r[3])) + ((r[4] + r[5]) + (r[6] + r[7]));
    }
    Fv[n] = sblk[0] + sblk[1];
  } else if (bid < 608) {      // ehTf fragment-linear from e[c][k]
    int t = bid - 96;
    int k0 = (t >> 2) * 64, c0 = (t & 3) * 64;
    int tx = tid & 63, ty = tid >> 6;
#pragma unroll
    for (int i = 0; i < 16; ++i) {
      int cl = i * 4 + ty;
      sm[cl][tx] = e[(size_t)(c0 + cl) * KD + k0 + tx];
    }
    __syncthreads();
#pragma unroll
    for (int p = 0; p < 2; ++p) {
      int i = tid + p * 256;
      int kl = i & 63, cg = i >> 6;
      int kkl = cg >> 2, gg = cg & 3;
      int chb = kkl * 32 + gg * 8;
      half8 h;
#pragma unroll
      for (int j = 0; j < 8; ++j) h[j] = (f16)sm[chb + j][kl];
      int tile = (k0 >> 4) + (kl >> 4);
      int kk = (c0 >> 5) + kkl;
      int lanef = gg * 16 + (kl & 15);
      *(half8*)(ehTf + ((size_t)(tile * 8 + kk) * 64 + lanef) * 8) = h;
    }
  } else {                     // xhTf fragment-linear from x[b][c][hw]
    int t = bid - 608;
    int b = t >> 6, rem = t & 63;
    int hw0 = (rem >> 2) * 64, c0 = (rem & 3) * 64;
    int tx = tid & 63, ty = tid >> 6;
#pragma unroll
    for (int i = 0; i < 16; ++i) {
      int cl = i * 4 + ty;
      sm[cl][tx] = x[((size_t)(b * 256 + c0 + cl) << 10) + hw0 + tx];
    }
    __syncthreads();
#pragma unroll
    for (int p = 0; p < 2; ++p) {
      int i = tid + p * 256;
      int nl = i & 63, cg = i >> 6;
      int kkl = cg >> 2, gg = cg & 3;
      int chb = kkl * 32 + gg * 8;
      half8 h;
#pragma unroll
      for (int j = 0; j < 8; ++j) h[j] = (f16)sm[chb + j][nl];
      int rt = b * 64 + (hw0 >> 4) + (nl >> 4);
      int kk = (c0 >> 5) + kkl;
      int lanef = gg * 16 + (nl & 15);
      *(half8*)(xhTf + ((size_t)(rt * 8 + kk) * 64 + lanef) * 8) = h;
    }
  }
}

// m97-geometry MFMA distance GEMM + T3/T4 counted-vmcnt pipeline.
// Grid 4096 = rowblk(128; 128r) x colblk(32; 256c). 8 waves 2x4, wave-tile
// 64x64; launch_bounds(512,4) => 2 WGs/CU. BK=32, 8 steps; 24 x 1KB
// blocks/step staged by gl16 (3/wave), TRIPLE-buffered (72KB+4KB red).
// Schedule/step: issue gl16(s+2) -> ds_read(s) -> MFMA -> vmcnt(3)
// (step s+1's loads guaranteed done; 3 newest stay in flight across the raw
// s_barrier -- never drain to 0 in the loop).
__global__ __launch_bounds__(512, 4) void k_gemm(const f16* __restrict__ xhTf,
                                                 const f16* __restrict__ ehTf,
                                                 const float* __restrict__ eev,
                                                 u32* __restrict__ m1,
                                                 u16* __restrict__ m2) {
  __shared__ __align__(16) f16 ldsbuf[3 * BUFSZ];        // [buf][block][512 f16]
  __shared__ u32 red1[4][128];
  __shared__ u32 red2[4][128];
  const int tid = threadIdx.x;
  const int lane = tid & 63, w = tid >> 6;
  const int wm = w >> 2, wn = w & 3;
  const int l15 = lane & 15, g = lane >> 4;
  const int colblk = blockIdx.x & 31;
  const int rowblk = (int)blockIdx.x >> 5;

  // 24 blocks/step: A = row-tiles rowblk*8+i (i<8), B = col-tiles colblk*16+i (i<16)
  const int blk0 = w * 3;
  const f16* gsrc[3];
#pragma unroll
  for (int i = 0; i < 3; ++i) {
    int b = blk0 + i;
    gsrc[i] = ((b < 8) ? (xhTf + (size_t)(rowblk * 8 + b) * 4096)
                       : (ehTf + (size_t)(colblk * 16 + (b - 8)) * 4096)) + lane * 8;
  }

  f32x4 acc[4][4];
#pragma unroll
  for (int i = 0; i < 4; ++i)
#pragma unroll
    for (int j = 0; j < 4; ++j) acc[i][j] = (f32x4){0.f, 0.f, 0.f, 0.f};

  // prologue: stage steps 0 and 1 into buffers 0 and 1
#pragma unroll
  for (int i = 0; i < 3; ++i) gl16(gsrc[i], ldsbuf + (blk0 + i) * 512);
#pragma unroll
  for (int i = 0; i < 3; ++i) gl16(gsrc[i] + 512, ldsbuf + BUFSZ + (blk0 + i) * 512);
  asm volatile("s_waitcnt vmcnt(3)" ::: "memory");   // buffer 0 complete
  __builtin_amdgcn_s_barrier();

  const f16* lrA = ldsbuf + (wm * 4) * 512 + lane * 8;        // + cur + mt*512
  const f16* lrB = ldsbuf + (8 + wn * 4) * 512 + lane * 8;    // + cur + nt*512

#pragma unroll
  for (int s = 0; s < 8; ++s) {
    const int cur = (s % 3) * BUFSZ;
    if (s < 6) {
      const int pre = ((s + 2) % 3) * BUFSZ;
#pragma unroll
      for (int i = 0; i < 3; ++i)
        gl16(gsrc[i] + (s + 2) * 512, ldsbuf + pre + (blk0 + i) * 512);
    }
    half8 af[4], bf[4];
#pragma unroll
    for (int mt = 0; mt < 4; ++mt) af[mt] = *(const half8*)(lrA + cur + mt * 512);
#pragma unroll
    for (int nt = 0; nt < 4; ++nt) bf[nt] = *(const half8*)(lrB + cur + nt * 512);
    __builtin_amdgcn_s_setprio(1);
#pragma unroll
    for (int mt = 0; mt < 4; ++mt)
#pragma unroll
      for (int nt = 0; nt < 4; ++nt)
        acc[mt][nt] = __builtin_amdgcn_mfma_f32_16x16x32_f16(af[mt], bf[nt], acc[mt][nt], 0, 0, 0);
    __builtin_amdgcn_s_setprio(0);
    if (s < 6) {
      asm volatile("s_waitcnt vmcnt(3)" ::: "memory");  // step s+1 buffer ready
      __builtin_amdgcn_s_barrier();
    } else if (s == 6) {
      asm volatile("s_waitcnt vmcnt(0)" ::: "memory");  // last buffer ready
      __builtin_amdgcn_s_barrier();
    }
  }

  // epilogue: keys = float-bits(d16) top-24 | col8 (col-in-colblk)
  float ee16[4];
#pragma unroll
  for (int nt = 0; nt < 4; ++nt)
    ee16[nt] = eev[colblk * 256 + wn * 64 + nt * 16 + l15] + 16.0f;
#pragma unroll
  for (int mt = 0; mt < 4; ++mt) {
#pragma unroll
    for (int r = 0; r < 4; ++r) {
      u32 s1 = 0xFFFFFFFFu, s2 = 0xFFFFFFFFu;
#pragma unroll
      for (int nt = 0; nt < 4; ++nt) {
        float d16 = fmaf(-2.f, acc[mt][nt][r], ee16[nt]);
        u32 k = (__float_as_uint(d16) & 0xFFFFFF00u) | (u32)(wn * 64 + nt * 16 + l15);
        u32 t = umax32(s1, k);
        s1 = umin32(s1, k);
        s2 = umin32(s2, t);
      }
#pragma unroll
      for (int msk = 1; msk < 16; msk <<= 1) {
        u32 o1 = (u32)__shfl_xor((int)s1, msk, 64);
        u32 o2 = (u32)__shfl_xor((int)s2, msk, 64);
        u32 t = umax32(s1, o1);
        s1 = umin32(s1, o1);
        s2 = umin32(umin32(s2, o2), t);
      }
      if (l15 == 0) {
        int rl = wm * 64 + mt * 16 + g * 4 + r;
        red1[wn][rl] = s1;
        red2[wn][rl] = s2;
      }
    }
  }
  __syncthreads();
  if (tid < 128) {
    u32 k1 = red1[0][tid], k2 = red2[0][tid];
#pragma unroll
    for (int wv = 1; wv < 4; ++wv) {
      u32 a = red1[wv][tid], b2 = red2[wv][tid];
      u32 t = umax32(k1, a);
      k1 = umin32(k1, a);
      k2 = umin32(k2, umin32(t, b2));
    }
    int row = rowblk * 128 + tid;
    m1[(size_t)colblk * 16384 + row] = k1;                 // contiguous 512B/WG
    float d2 = __uint_as_float(k2 & 0xFFFFFF00u);          // d16-domain lower bound
    float tq = fmaxf(fminf(d2 * 2048.0f, 65535.f), 0.f);   // NaN-safe
    m2[(size_t)colblk * 16384 + row] = (u16)(u32)tq;       // contiguous 256B/WG
  }
}

// one wave per row: window test over 32 colblk top1/top2 (transposed m1/m2,
// L2-resident); direct write when unambiguous; else exact rescore + enqueue.
__global__ __launch_bounds__(256) void k_sel(const float* __restrict__ x,
                                             const float* __restrict__ e,
                                             const u32* __restrict__ m1,
                                             const u16* __restrict__ m2,
                                             const float* __restrict__ Fv,
                                             const float* __restrict__ eev,
                                             const u32* __restrict__ eemax,
                                             u64* __restrict__ best,
                                             u32* __restrict__ cnt,
                                             u32* __restrict__ list) {
  const int row = blockIdx.x * 4 + (threadIdx.x >> 6);
  const int lane = threadIdx.x & 63;
  u32 m1v = 0xFFFFFFFFu;
  u32 m2v = 0xFFFFu;
  if (lane < 32) {
    m1v = m1[(size_t)lane * 16384 + row];
    m2v = (u32)m2[(size_t)lane * 16384 + row];
  }
  u32 gk = m1v;
#pragma unroll
  for (int msk = 1; msk < 64; msk <<= 1) gk = umin32(gk, (u32)__shfl_xor((int)gk, msk, 64));
  const float F = Fv[row];
  const float eps = 0x1p-9f * sqrtf(F * __uint_as_float(*eemax)) + 4e-4f;
  const float thr = (__uint_as_float(gk & 0xFFFFFF00u) - 16.0f) + 2.f * eps + 1e-3f;

  const bool f1 = (lane < 32) && (__uint_as_float(m1v & 0xFFFFFF00u) - 16.0f <= thr);
  const bool trig = (lane < 32) && ((float)m2v * (1.0f / 2048.0f) - 16.0f <= thr);
  const u64 bal = __ballot(f1);
  const bool anyt = __any(trig);

  const int col = lane * 256 + (int)(m1v & 255u);
  const int b = row >> 10, hw = row & 1023;

  if (__popcll(bal) == 1 && !anyt) {
    if (f1) best[row] = (u64)(unsigned)col;        // unambiguous: key 0
  } else {
    if (f1) {
      float d = exact_d(x, e, b, hw, col, F, eev);
      atomicMin(&best[row], pack64(d, (unsigned)col));
    }
    if (trig) {
      u32 slot = atomicAdd(cnt, 1u);
      if (slot < LCAP) list[slot] = (u32)((row << 5) | lane);
      else {   // overflow fallback (correctness only, ~never)
        for (int j = 0; j < 256; ++j) {
          int cj = lane * 256 + j;
          float d = exact_d(x, e, b, hw, cj, F, eev);
          atomicMin(&best[row], pack64(d, (unsigned)cj));
        }
      }
    }
  }
}

// full-colblk (256-col) exact rescore: wave per task, 4 cols/lane
__global__ __launch_bounds__(256) void k_chunk(const float* __restrict__ x,
                                               const float* __restrict__ e,
                                               const float* __restrict__ Fv,
                                               const float* __restrict__ eev,
                                               const u32* __restrict__ cnt,
                                               const u32* __restrict__ list,
                                               u64* __restrict__ best) {
  u32 n = *cnt; if (n > LCAP) n = LCAP;
  const int lane = threadIdx.x & 63;
  for (u32 t = blockIdx.x * 4 + (threadIdx.x >> 6); t < n; t += gridDim.x * 4) {
    u32 v = list[t];
    int row = (int)(v >> 5), cb = (int)(v & 31u);
    int b = row >> 10, hw = row & 1023;
    float F = Fv[row];
    int base = cb * 256 + lane;
    float a0 = 0.f, a1 = 0.f, a2 = 0.f, a3 = 0.f;
#pragma unroll 8
    for (int c = 0; c < 256; ++c) {
      float xv = x[((size_t)(b * 256 + c) << 10) + hw];
      const float* ep = e + (size_t)c * KD + base;
      a0 = fmaf(xv, ep[0], a0);
      a1 = fmaf(xv, ep[64], a1);
      a2 = fmaf(xv, ep[128], a2);
      a3 = fmaf(xv, ep[192], a3);
    }
    float acc4[4] = {a0, a1, a2, a3};
#pragma unroll
    for (int q = 0; q < 4; ++q) {
      int col = base + q * 64;
      float t2 = fmaf(-2.f, acc4[q], F);
      float d = t2 + eev[col];
      atomicMin(&best[row], pack64(d, (unsigned)col));
    }
  }
}

// extract idx (u16) + eind + counts
__global__ __launch_bounds__(256) void k_ind(const u64* __restrict__ best,
                                             u16* __restrict__ idx16,
                                             int* __restrict__ counts,
                                             float* __restrict__ out) {
  int n = blockIdx.x * 256 + threadIdx.x;
  u32 idx = (u32)(best[n] & 0xFFFFFFFFull);
  idx16[n] = (u16)idx;
  out[EIND_OFF + n] = (float)idx;
  atomicAdd(&counts[idx], 1);
}

// quantize + straight-through + diff partials (float4-vectorized)
__global__ __launch_bounds__(256) void k_out(const float* __restrict__ x,
                                             const float* __restrict__ e,
                                             const u16* __restrict__ idx16,
                                             float* __restrict__ out,
                                             float* __restrict__ dpart) {
  __shared__ float sd[256];
  int tid = threadIdx.x;
  float local = 0.0f;
  for (size_t v = (size_t)blockIdx.x * 256 + tid; v < 1048576ull; v += 262144ull) {
    size_t i = v * 4;
    int hw = (int)(i & 1023);
    int c = (int)((i >> 10) & 255);
    int bb = (int)(i >> 18);
    int n = (bb << 10) + hw;
    ushort4 id4 = *(const ushort4*)(idx16 + n);
    float4 xv = *(const float4*)(x + i);
    const float* ec = e + (size_t)c * KD;
    float d0 = ec[id4.x] - xv.x;
    float d1 = ec[id4.y] - xv.y;
    float d2 = ec[id4.z] - xv.z;
    float d3 = ec[id4.w] - xv.w;
    float4 o = {xv.x + d0, xv.y + d1, xv.z + d2, xv.w + d3};
    *(float4*)(out + i) = o;
    local += d0 * d0 + d1 * d1 + d2 * d2 + d3 * d3;
  }
  sd[tid] = local;
  __syncthreads();
  for (int s = 128; s > 0; s >>= 1) {
    if (tid < s) sd[tid] += sd[tid + s];
    __syncthreads();
  }
  if (tid == 0) dpart[blockIdx.x] = sd[0];
}

__global__ __launch_bounds__(256) void k_perp(const int* __restrict__ counts,
                                              const float* __restrict__ dpart,
                                              float* __restrict__ out) {
  __shared__ float sd[256];
  int tid = threadIdx.x;
  float s = 0.0f;
  for (int k = tid; k < KD; k += 256) {
    float p = (float)counts[k] * (1.0f / 16384.0f);
    s += p * logf(p + 1e-10f);
  }
  sd[tid] = s;
  __syncthreads();
  for (int t = 128; t > 0; t >>= 1) {
    if (tid < t) sd[tid] += sd[tid + t];
    __syncthreads();
  }
  float S = sd[0];
  __syncthreads();
  float d = 0.0f;
  for (int t = tid; t < 1024; t += 256) d += dpart[t];
  sd[tid] = d;
  __syncthreads();
  for (int t = 128; t > 0; t >>= 1) {
    if (tid < t) sd[tid] += sd[tid + t];
    __syncthreads();
  }
  if (tid == 0) {
    out[DIFF_OFF] = sd[0] * (1.0f / 4194304.0f);
    out[PERP_OFF] = expf(-S);
  }
}

extern "C" void kernel_launch(void* const* d_in, const int* in_sizes, int n_in,
                              void* d_out, int out_size, void* d_ws, size_t ws_size,
                              hipStream_t stream) {
  const float* x = (const float*)d_in[0];   // [16,256,32,32]
  const float* e = (const float*)d_in[1];   // [256,8192]
  float* out = (float*)d_out;
  char* dc = (char*)d_out;
  char* ws = (char*)d_ws;

  u64* best = (u64*)(ws);
  float* Fv = (float*)(ws + 131072);
  float* eev = (float*)(ws + 196608);
  u16* idx16 = (u16*)(ws + 229376);
  int* counts = (int*)(ws + 262144);
  float* dpart = (float*)(ws + 294912);
  u32* eemax = (u32*)(ws + 299008);
  u32* cnt = (u32*)(ws + 299012);

  f16* ehTf = (f16*)(dc);
  f16* xhTf = (f16*)(dc + 4194304);
  u32* m1 = (u32*)(dc + 12582912);
  u16* m2 = (u16*)(dc + 14680064);
  u32* list = (u32*)(dc + 15728640);

  hipMemsetAsync(best, 0xFF, 131072, stream);
  hipMemsetAsync(counts, 0, 36872, stream);   // counts+dpart+eemax+cnt

  k_prep<<<1632, 256, 0, stream>>>(x, e, Fv, eev, eemax, ehTf, xhTf);
  k_gemm<<<4096, 512, 0, stream>>>(xhTf, ehTf, eev, m1, m2);
  k_sel<<<4096, 256, 0, stream>>>(x, e, m1, m2, Fv, eev, eemax, best, cnt, list);
  k_chunk<<<1024, 256, 0, stream>>>(x, e, Fv, eev, cnt, list, best);
  k_ind<<<64, 256, 0, stream>>>(best, idx16, counts, out);
  k_out<<<1024, 256, 0, stream>>>(x, e, idx16, out, dpart);
  k_perp<<<1, 256, 0, stream>>>(counts, dpart, out);
}